// Round 5
// baseline (9998.795 us; speedup 1.0000x reference)
//
#include <hip/hip_runtime.h>
#include <math.h>

#define T_ 1024
#define NT_ 4096
#define MASKSELF64 -50000.0
#define MASKSELF32 -50000.0f

// ---------------- embedding (fp64) ----------------
__global__ __launch_bounds__(256)
void embed_kernel(const float* __restrict__ x_enc, const float* __restrict__ x_mark_enc,
                  const float* __restrict__ x_dec, const float* __restrict__ x_mark_dec,
                  const float* __restrict__ conv_w, const float* __restrict__ mark_w,
                  double* __restrict__ h) {
  int bt = blockIdx.x;
  int b = bt >> 10, t = bt & 1023;
  __shared__ double xs[3][7];
  __shared__ double xm[4];
  int tid = threadIdx.x;
  if (tid < 21) {
    int k = tid / 7, i = tid % 7;
    int tt = t + k - 1;
    if (tt < 0) tt += 1024;
    if (tt >= 1024) tt -= 1024;
    xs[k][i] = (double)((tt < 768) ? x_enc[((size_t)b*768 + tt)*7 + i]
                                   : x_dec[((size_t)b*512 + (tt - 512))*7 + i]);
  }
  if (tid >= 32 && tid < 36) {
    int m = tid - 32;
    xm[m] = (double)((t < 768) ? x_mark_enc[((size_t)b*768 + t)*4 + m]
                               : x_mark_dec[((size_t)b*512 + (t - 512))*4 + m]);
  }
  __syncthreads();
  for (int o = tid; o < 512; o += 256) {
    double acc = 0.0;
    #pragma unroll
    for (int k = 0; k < 3; ++k)
      #pragma unroll
      for (int i = 0; i < 7; ++i)
        acc += xs[k][i] * (double)conv_w[(o*7 + i)*3 + k];
    #pragma unroll
    for (int m = 0; m < 4; ++m) acc += xm[m] * (double)mark_w[m*512 + o];
    int j2 = o & ~1;
    double dv = exp((double)j2 * (-9.210340371976184 / 512.0));
    double arg = (double)t * dv;
    acc += (o & 1) ? cos(arg) : sin(arg);
    h[((size_t)b*1024 + t)*512 + o] = acc;
  }
}

// ---------------- fp64 scalar GEMM 64x64x16, 4x4 microtile (R2-proven numerics) ----------------
// microtile remapped to row=ty+16i, col=tx+16j (conflict-free LDS reads; same arithmetic)
// flags: 1=+bias, 2=gelu(exact), 4=qkv layout, 8=dup f32 store (qkv layout only)
__global__ __launch_bounds__(256)
void dgemm_kernel(const double* __restrict__ A, const float* __restrict__ Bm,
                  const float* __restrict__ bias, double* __restrict__ C,
                  float* __restrict__ C32, int N, int K, int flags) {
  __shared__ double As[16][65];
  __shared__ double Bs[16][66];
  int tid = threadIdx.x;
  int tx = tid & 15, ty = tid >> 4;
  int arow = blockIdx.x * 64;
  int bcol = blockIdx.y * 64;
  double acc[4][4];
  #pragma unroll
  for (int i=0;i<4;++i)
    #pragma unroll
    for (int j=0;j<4;++j) acc[i][j]=0.0;
  for (int k0 = 0; k0 < K; k0 += 16) {
    #pragma unroll
    for (int q = 0; q < 2; ++q) {
      int e = tid*2 + q;
      int r = e >> 3, c2 = (e & 7)*2;
      double2 av = *(const double2*)(A + (size_t)(arow + r)*K + k0 + c2);
      As[c2][r] = av.x; As[c2+1][r] = av.y;
      int kk = e >> 5, cc = (e & 31)*2;
      float2 bv = *(const float2*)(Bm + (size_t)(k0+kk)*N + bcol + cc);
      Bs[kk][cc] = (double)bv.x; Bs[kk][cc+1] = (double)bv.y;
    }
    __syncthreads();
    #pragma unroll
    for (int kk=0;kk<16;++kk) {
      double a[4], bb[4];
      #pragma unroll
      for (int i=0;i<4;++i) a[i] = As[kk][ty + 16*i];
      #pragma unroll
      for (int j=0;j<4;++j) bb[j] = Bs[kk][tx + 16*j];
      #pragma unroll
      for (int i=0;i<4;++i)
        #pragma unroll
        for (int j=0;j<4;++j) acc[i][j] += a[i]*bb[j];
    }
    __syncthreads();
  }
  #pragma unroll
  for (int i=0;i<4;++i) {
    int row = arow + ty + 16*i;
    #pragma unroll
    for (int j=0;j<4;++j) {
      int col = bcol + tx + 16*j;
      double cv = acc[i][j];
      if (flags & 1) cv += (double)bias[col];
      if (flags & 2) cv = 0.5*cv*(1.0 + erf(cv*0.70710678118654752440));
      if (flags & 4) {
        int b = row >> 10, t = row & 1023;
        int hd = col >> 6, dd = col & 63;
        size_t idx = (((size_t)b*8 + hd)*1024 + t)*64 + dd;
        C[idx] = cv;
        if (flags & 8) C32[idx] = (float)cv;
      } else {
        C[(size_t)row*N + col] = cv;
      }
    }
  }
}

// ---------------- fp32 GEMM 128x128x16, 8x8 microtile (conflict-free remap) ----------------
// flags: 1=+bias, 2=gelu(exact), 4=qkv layout
__global__ __launch_bounds__(256)
void sgemm_kernel(const float* __restrict__ A, const float* __restrict__ Bm,
                  const float* __restrict__ bias, float* __restrict__ C,
                  int N, int K, int flags) {
  __shared__ float As[16][128];
  __shared__ float Bs[16][128];
  int tid = threadIdx.x;
  int tx = tid & 15, ty = tid >> 4;
  float acc[8][8];
  #pragma unroll
  for (int i=0;i<8;++i)
    #pragma unroll
    for (int j=0;j<8;++j) acc[i][j]=0.f;
  const int arow = blockIdx.x*128;
  const int bcol = blockIdx.y*128;
  for (int k0 = 0; k0 < K; k0 += 16) {
    #pragma unroll
    for (int q = 0; q < 2; ++q) {
      int f4 = tid*2 + q;
      int r = f4 >> 2, c4 = f4 & 3;
      float4 av = *(const float4*)(A + (size_t)(arow + r)*K + k0 + c4*4);
      As[c4*4+0][r]=av.x; As[c4*4+1][r]=av.y; As[c4*4+2][r]=av.z; As[c4*4+3][r]=av.w;
      int kk = f4 >> 5, cc = f4 & 31;
      *(float4*)&Bs[kk][cc*4] = *(const float4*)(Bm + (size_t)(k0+kk)*N + bcol + cc*4);
    }
    __syncthreads();
    #pragma unroll
    for (int kk=0;kk<16;++kk) {
      float a[8], bb[8];
      #pragma unroll
      for (int i=0;i<8;++i) a[i] = As[kk][ty + 16*i];
      #pragma unroll
      for (int j=0;j<8;++j) bb[j] = Bs[kk][tx + 16*j];
      #pragma unroll
      for (int i=0;i<8;++i)
        #pragma unroll
        for (int j=0;j<8;++j) acc[i][j] += a[i]*bb[j];
    }
    __syncthreads();
  }
  #pragma unroll
  for (int i=0;i<8;++i) {
    int row = arow + ty + 16*i;
    #pragma unroll
    for (int j=0;j<8;++j) {
      int col = bcol + tx + 16*j;
      float cv = acc[i][j];
      if (flags & 1) cv += bias[col];
      if (flags & 2) cv = 0.5f*cv*(1.0f + erff(cv*0.70710678118654752f));
      if (flags & 4) {
        int b = row >> 10, t = row & 1023;
        int hd = col >> 6, dd = col & 63;
        C[(((size_t)b*8 + hd)*1024 + t)*64 + dd] = cv;
      } else {
        C[(size_t)row*N + col] = cv;
      }
    }
  }
}

// ---------------- LSH bucket assignment + per-round counting sort (fp64) ----------------
__global__ __launch_bounds__(256)
void bucket_sort_kernel(const double* __restrict__ qk, const float* __restrict__ rot,
                        int* __restrict__ sticker) {
  int bh = blockIdx.x >> 2, r = blockIdx.x & 3;
  __shared__ double rots[64][17];
  __shared__ unsigned char bucket[1024];
  __shared__ int cnt[32];
  __shared__ int off[32];
  int tid = threadIdx.x;
  for (int idx = tid; idx < 1024; idx += 256) {
    int f = idx >> 4, i = idx & 15;
    rots[f][i] = (double)rot[(f*4 + r)*16 + i];
  }
  if (tid < 32) cnt[tid] = 0;
  __syncthreads();
  for (int t = tid; t < 1024; t += 256) {
    const double* q = qk + ((size_t)bh*1024 + t)*64;
    double rv[16];
    #pragma unroll
    for (int i=0;i<16;++i) rv[i]=0.0;
    for (int f=0; f<64; ++f) {
      double qf = q[f];
      #pragma unroll
      for (int i=0;i<16;++i) rv[i] += qf * rots[f][i];
    }
    int best = 0; double bv = rv[0];
    #pragma unroll
    for (int i=1;i<16;++i) if (rv[i] > bv) { bv=rv[i]; best=i; }
    #pragma unroll
    for (int i=0;i<16;++i) { double nv = -rv[i]; if (nv > bv) { bv=nv; best=16+i; } }
    bucket[t] = (unsigned char)best;
    atomicAdd(&cnt[best], 1);
  }
  __syncthreads();
  if (tid == 0) {
    int s = 0;
    for (int k=0;k<32;++k) { off[k]=s; s+=cnt[k]; }
  }
  __syncthreads();
  if (tid < 32) {
    int pos = off[tid];
    int* outp = sticker + (size_t)bh*NT_ + r*1024;
    for (int t=0;t<1024;++t)
      if (bucket[t] == (unsigned char)tid) outp[pos++] = t;
  }
}

// ---------------- chunked LSH attention fp64 ----------------
__global__ __launch_bounds__(256)
void lsh_attn_kernel(const double* __restrict__ qk, const double* __restrict__ v,
                     const int* __restrict__ sticker,
                     double* __restrict__ obuf, double* __restrict__ lse, int bh0) {
  int bh_l = blockIdx.x >> 7;
  int bh = bh0 + bh_l;
  int c  = blockIdx.x & 127;
  int cprev = (c + 127) & 127;
  __shared__ double kv[64][66];
  __shared__ double pp[32][66];
  __shared__ double rnorm[64];
  __shared__ int tk[64];
  int tid = threadIdx.x;
  if (tid < 64) {
    int chunk = (tid < 32) ? c : cprev;
    tk[tid] = sticker[(size_t)bh*NT_ + chunk*32 + (tid & 31)];
  }
  __syncthreads();
  for (int idx = tid; idx < 2048; idx += 256) {
    int j = idx >> 5, c2 = (idx & 31)*2;
    *(double2*)&kv[j][c2] = *(const double2*)(qk + ((size_t)bh*1024 + tk[j])*64 + c2);
  }
  __syncthreads();
  if (tid < 64) {
    double s = 0.0;
    #pragma unroll
    for (int f=0; f<64; ++f) { double x = kv[tid][f]; s += x*x; }
    rnorm[tid] = 1.0 / fmax(sqrt(s), 1e-12);
  }
  __syncthreads();
  int i = tid >> 3, sub = tid & 7;
  int ti = tk[i];
  double dots[8];
  double dmax = -1.0e300;
  #pragma unroll
  for (int jj=0; jj<8; ++jj) {
    int j = sub*8 + jj;
    double s = 0.0;
    #pragma unroll
    for (int f=0; f<64; ++f) s += kv[i][f] * kv[j][f];
    s *= rnorm[j] * 0.125;
    if (ti == tk[j]) s = MASKSELF64;
    dots[jj] = s;
    dmax = fmax(dmax, s);
  }
  #pragma unroll
  for (int w=1; w<8; w<<=1) dmax = fmax(dmax, __shfl_xor(dmax, w, 64));
  double esum = 0.0;
  #pragma unroll
  for (int jj=0; jj<8; ++jj) {
    double e = exp(dots[jj] - dmax);
    esum += e;
    pp[i][sub*8+jj] = e;
  }
  #pragma unroll
  for (int w=1; w<8; w<<=1) esum += __shfl_xor(esum, w, 64);
  __syncthreads();
  for (int idx = tid; idx < 2048; idx += 256) {
    int j = idx >> 5, c2 = (idx & 31)*2;
    *(double2*)&kv[j][c2] = *(const double2*)(v + ((size_t)bh*1024 + tk[j])*64 + c2);
  }
  __syncthreads();
  double ov[8];
  #pragma unroll
  for (int dd=0;dd<8;++dd) ov[dd]=0.0;
  for (int j=0;j<64;++j) {
    double p = pp[i][j];
    #pragma unroll
    for (int dd=0;dd<8;++dd) ov[dd] += p * kv[j][sub*8+dd];
  }
  double rinv = 1.0 / esum;
  int r = c >> 5;
  size_t ob = (((size_t)bh_l*4 + r)*1024 + ti)*64 + sub*8;
  #pragma unroll
  for (int dd=0;dd<8;++dd) obuf[ob + dd] = ov[dd]*rinv;
  if (sub == 0) lse[((size_t)bh*4 + r)*1024 + ti] = log(esum) + dmax;
}

// ---------------- combine rounds (fp64) ----------------
__global__ __launch_bounds__(256)
void combine_kernel(const double* __restrict__ obuf, const double* __restrict__ lse,
                    double* __restrict__ comb, int bh0) {
  int g = blockIdx.x*4 + (threadIdx.x >> 6);
  int bh_l = g >> 10, t = g & 1023;
  int bh = bh0 + bh_l;
  int d = threadIdx.x & 63;
  double l[4];
  #pragma unroll
  for (int r=0;r<4;++r) l[r] = lse[((size_t)bh*4 + r)*1024 + t];
  double m = fmax(fmax(l[0],l[1]), fmax(l[2],l[3]));
  double e[4], s=0.0;
  #pragma unroll
  for (int r=0;r<4;++r){ e[r]=exp(l[r]-m); s+=e[r]; }
  double rs = 1.0/s;
  double o = 0.0;
  #pragma unroll
  for (int r=0;r<4;++r)
    o += e[r]*rs * obuf[(((size_t)bh_l*4 + r)*1024 + t)*64 + d];
  int b = bh >> 3, hd = bh & 7;
  comb[((size_t)b*1024 + t)*512 + hd*64 + d] = o;
}

// ---------------- chunked LSH attention fp32 (layer-2 value path) ----------------
__global__ __launch_bounds__(256)
void lsh_attn32_kernel(const float* __restrict__ qk, const float* __restrict__ v,
                       const int* __restrict__ sticker,
                       float* __restrict__ obuf, float* __restrict__ lse, int bh0) {
  int bh_l = blockIdx.x >> 7;
  int bh = bh0 + bh_l;
  int c  = blockIdx.x & 127;
  int cprev = (c + 127) & 127;
  __shared__ float kv[64][68];
  __shared__ float pp[32][68];
  __shared__ float rnorm[64];
  __shared__ int tk[64];
  int tid = threadIdx.x;
  if (tid < 64) {
    int chunk = (tid < 32) ? c : cprev;
    tk[tid] = sticker[(size_t)bh*NT_ + chunk*32 + (tid & 31)];
  }
  __syncthreads();
  for (int idx = tid; idx < 1024; idx += 256) {
    int j = idx >> 4, c4 = (idx & 15)*4;
    *(float4*)&kv[j][c4] = *(const float4*)(qk + ((size_t)bh*1024 + tk[j])*64 + c4);
  }
  __syncthreads();
  if (tid < 64) {
    float s = 0.f;
    #pragma unroll
    for (int f=0; f<64; ++f) { float x = kv[tid][f]; s += x*x; }
    rnorm[tid] = 1.0f / fmaxf(sqrtf(s), 1e-12f);
  }
  __syncthreads();
  int i = tid >> 3, sub = tid & 7;
  int ti = tk[i];
  float dots[8];
  float dmax = -1.0e30f;
  #pragma unroll
  for (int jj=0; jj<8; ++jj) {
    int j = sub*8 + jj;
    float s = 0.f;
    #pragma unroll
    for (int f=0; f<64; ++f) s += kv[i][f] * kv[j][f];
    s *= rnorm[j] * 0.125f;
    if (ti == tk[j]) s = MASKSELF32;
    dots[jj] = s;
    dmax = fmaxf(dmax, s);
  }
  #pragma unroll
  for (int w=1; w<8; w<<=1) dmax = fmaxf(dmax, __shfl_xor(dmax, w, 64));
  float esum = 0.f;
  #pragma unroll
  for (int jj=0; jj<8; ++jj) {
    float e = expf(dots[jj] - dmax);
    esum += e;
    pp[i][sub*8+jj] = e;
  }
  #pragma unroll
  for (int w=1; w<8; w<<=1) esum += __shfl_xor(esum, w, 64);
  __syncthreads();
  for (int idx = tid; idx < 1024; idx += 256) {
    int j = idx >> 4, c4 = (idx & 15)*4;
    *(float4*)&kv[j][c4] = *(const float4*)(v + ((size_t)bh*1024 + tk[j])*64 + c4);
  }
  __syncthreads();
  float ov[8];
  #pragma unroll
  for (int dd=0;dd<8;++dd) ov[dd]=0.f;
  for (int j=0;j<64;++j) {
    float p = pp[i][j];
    #pragma unroll
    for (int dd=0;dd<8;++dd) ov[dd] += p * kv[j][sub*8+dd];
  }
  float rinv = 1.0f / esum;
  int r = c >> 5;
  size_t ob = (((size_t)bh_l*4 + r)*1024 + ti)*64 + sub*8;
  #pragma unroll
  for (int dd=0;dd<8;++dd) obuf[ob + dd] = ov[dd]*rinv;
  if (sub == 0) lse[((size_t)bh*4 + r)*1024 + ti] = logf(esum) + dmax;
}

// ---------------- combine rounds (fp32) ----------------
__global__ __launch_bounds__(256)
void combine32_kernel(const float* __restrict__ obuf, const float* __restrict__ lse,
                      float* __restrict__ comb, int bh0) {
  int g = blockIdx.x*4 + (threadIdx.x >> 6);
  int bh_l = g >> 10, t = g & 1023;
  int bh = bh0 + bh_l;
  int d = threadIdx.x & 63;
  float l[4];
  #pragma unroll
  for (int r=0;r<4;++r) l[r] = lse[((size_t)bh*4 + r)*1024 + t];
  float m = fmaxf(fmaxf(l[0],l[1]), fmaxf(l[2],l[3]));
  float e[4], s=0.f;
  #pragma unroll
  for (int r=0;r<4;++r){ e[r]=expf(l[r]-m); s+=e[r]; }
  float rs = 1.0f/s;
  float o = 0.f;
  #pragma unroll
  for (int r=0;r<4;++r)
    o += e[r]*rs * obuf[(((size_t)bh_l*4 + r)*1024 + t)*64 + d];
  int b = bh >> 3, hd = bh & 7;
  comb[((size_t)b*1024 + t)*512 + hd*64 + d] = o;
}

// ---------------- layernorm fp64 (optional residual, optional f32 dup) ----------------
__global__ __launch_bounds__(256)
void ln_kernel(const double* __restrict__ x, const double* __restrict__ res,
               const float* __restrict__ gw, const float* __restrict__ bw,
               double* __restrict__ outp, float* __restrict__ out32) {
  int row = blockIdx.x;
  int tid = threadIdx.x;
  const double* xr = x + (size_t)row*512;
  double v0 = xr[tid], v1 = xr[tid+256];
  if (res) { const double* rr = res + (size_t)row*512; v0 += rr[tid]; v1 += rr[tid+256]; }
  double s = v0 + v1;
  #pragma unroll
  for (int w=1; w<64; w<<=1) s += __shfl_xor(s, w, 64);
  __shared__ double red[4];
  int wid = tid >> 6, lane = tid & 63;
  if (lane == 0) red[wid] = s;
  __syncthreads();
  s = red[0]+red[1]+red[2]+red[3];
  double m = s * (1.0/512.0);
  double d0 = v0 - m, d1 = v1 - m;
  double q = d0*d0 + d1*d1;
  #pragma unroll
  for (int w=1; w<64; w<<=1) q += __shfl_xor(q, w, 64);
  __syncthreads();
  if (lane == 0) red[wid] = q;
  __syncthreads();
  q = red[0]+red[1]+red[2]+red[3];
  double var = q * (1.0/512.0);
  double rstd = 1.0 / sqrt(var + 1e-5);
  double o0 = d0*rstd*(double)gw[tid] + (double)bw[tid];
  double o1 = d1*rstd*(double)gw[tid+256] + (double)bw[tid+256];
  outp[(size_t)row*512 + tid]       = o0;
  outp[(size_t)row*512 + tid + 256] = o1;
  if (out32) {
    out32[(size_t)row*512 + tid]       = (float)o0;
    out32[(size_t)row*512 + tid + 256] = (float)o1;
  }
}

// ---------------- layernorm: x f64 + res f32 -> f32 ----------------
__global__ __launch_bounds__(256)
void lnmx_kernel(const double* __restrict__ x, const float* __restrict__ res,
                 const float* __restrict__ gw, const float* __restrict__ bw,
                 float* __restrict__ out32) {
  int row = blockIdx.x;
  int tid = threadIdx.x;
  const double* xr = x + (size_t)row*512;
  const float*  rr = res + (size_t)row*512;
  double v0 = xr[tid] + (double)rr[tid];
  double v1 = xr[tid+256] + (double)rr[tid+256];
  double s = v0 + v1;
  #pragma unroll
  for (int w=1; w<64; w<<=1) s += __shfl_xor(s, w, 64);
  __shared__ double red[4];
  int wid = tid >> 6, lane = tid & 63;
  if (lane == 0) red[wid] = s;
  __syncthreads();
  s = red[0]+red[1]+red[2]+red[3];
  double m = s * (1.0/512.0);
  double d0 = v0 - m, d1 = v1 - m;
  double q = d0*d0 + d1*d1;
  #pragma unroll
  for (int w=1; w<64; w<<=1) q += __shfl_xor(q, w, 64);
  __syncthreads();
  if (lane == 0) red[wid] = q;
  __syncthreads();
  q = red[0]+red[1]+red[2]+red[3];
  double rstd = 1.0 / sqrt(q * (1.0/512.0) + 1e-5);
  out32[(size_t)row*512 + tid]       = (float)(d0*rstd*(double)gw[tid] + (double)bw[tid]);
  out32[(size_t)row*512 + tid + 256] = (float)(d1*rstd*(double)gw[tid+256] + (double)bw[tid+256]);
}

// ---------------- layernorm f32 in/out (double stats), optional residual ----------------
__global__ __launch_bounds__(256)
void ln32_kernel(const float* __restrict__ x, const float* __restrict__ res,
                 const float* __restrict__ gw, const float* __restrict__ bw,
                 float* __restrict__ out32) {
  int row = blockIdx.x;
  int tid = threadIdx.x;
  const float* xr = x + (size_t)row*512;
  double v0 = (double)xr[tid], v1 = (double)xr[tid+256];
  if (res) { const float* rr = res + (size_t)row*512; v0 += (double)rr[tid]; v1 += (double)rr[tid+256]; }
  double s = v0 + v1;
  #pragma unroll
  for (int w=1; w<64; w<<=1) s += __shfl_xor(s, w, 64);
  __shared__ double red[4];
  int wid = tid >> 6, lane = tid & 63;
  if (lane == 0) red[wid] = s;
  __syncthreads();
  s = red[0]+red[1]+red[2]+red[3];
  double m = s * (1.0/512.0);
  double d0 = v0 - m, d1 = v1 - m;
  double q = d0*d0 + d1*d1;
  #pragma unroll
  for (int w=1; w<64; w<<=1) q += __shfl_xor(q, w, 64);
  __syncthreads();
  if (lane == 0) red[wid] = q;
  __syncthreads();
  q = red[0]+red[1]+red[2]+red[3];
  double rstd = 1.0 / sqrt(q * (1.0/512.0) + 1e-5);
  out32[(size_t)row*512 + tid]       = (float)(d0*rstd*(double)gw[tid] + (double)bw[tid]);
  out32[(size_t)row*512 + tid + 256] = (float)(d1*rstd*(double)gw[tid+256] + (double)bw[tid+256]);
}

// ---------------- final projection (f32 input, f64 accum, f32 store) ----------------
__global__ __launch_bounds__(64)
void proj_kernel(const float* __restrict__ hf, const float* __restrict__ pw,
                 const float* __restrict__ pb, float* __restrict__ outp) {
  int row = blockIdx.x;
  int b = row >> 8, tp = row & 255;
  const float* hr = hf + ((size_t)b*1024 + 768 + tp)*512;
  int lane = threadIdx.x;
  double acc[7];
  #pragma unroll
  for (int cc=0;cc<7;++cc) acc[cc]=0.0;
  for (int d = lane; d < 512; d += 64) {
    double hv = (double)hr[d];
    #pragma unroll
    for (int cc=0;cc<7;++cc) acc[cc] += hv * (double)pw[d*7 + cc];
  }
  #pragma unroll
  for (int cc=0;cc<7;++cc) {
    double s = acc[cc];
    #pragma unroll
    for (int w=32;w>=1;w>>=1) s += __shfl_xor(s, w, 64);
    if (lane == 0) outp[(size_t)row*7 + cc] = (float)(s + (double)pb[cc]);
  }
}

extern "C" void kernel_launch(void* const* d_in, const int* in_sizes, int n_in,
                              void* d_out, int out_size, void* d_ws, size_t ws_size,
                              hipStream_t stream) {
  (void)in_sizes; (void)n_in; (void)out_size; (void)ws_size;
  const float* x_enc      = (const float*)d_in[0];
  const float* x_mark_enc = (const float*)d_in[1];
  const float* x_dec      = (const float*)d_in[2];
  const float* x_mark_dec = (const float*)d_in[3];
  const float* conv_w     = (const float*)d_in[4];
  const float* mark_w     = (const float*)d_in[5];
  const float* qk_w       = (const float*)d_in[6];
  const float* v_w        = (const float*)d_in[7];
  const float* out_w      = (const float*)d_in[8];
  const float* out_b      = (const float*)d_in[9];
  const float* ln1_g      = (const float*)d_in[10];
  const float* ln1_b      = (const float*)d_in[11];
  const float* ln2_g      = (const float*)d_in[12];
  const float* ln2_b      = (const float*)d_in[13];
  const float* ffn_w1     = (const float*)d_in[14];
  const float* ffn_b1     = (const float*)d_in[15];
  const float* ffn_w2     = (const float*)d_in[16];
  const float* ffn_b2     = (const float*)d_in[17];
  const float* lnf_g      = (const float*)d_in[18];
  const float* lnf_b      = (const float*)d_in[19];
  const float* proj_w     = (const float*)d_in[20];
  const float* proj_b     = (const float*)d_in[21];
  const float* rotations  = (const float*)d_in[22];

  char* ws = (char*)d_ws;
  // f64 regions (layer-1 layout identical to round 2)
  double* h64   = (double*)(ws);               // A [0,64M)
  double* qk64  = (double*)(ws + 67108864);    // B [64,128M)  qk / ffn-hidden N/A
  double* v64   = (double*)(ws + 134217728);   // C [128,192M) v / comb
  double* obuf  = (double*)(ws + 201326592);   // D [192,224M) o_rounds 16-bh
  int*    stick = (int*)   (ws + 234881024);   // [224,226M)
  double* lse64 = (double*)(ws + 236978176);   // [226,230M)
  float*  lse32 = (float*) (ws + 236978176);
  double* comb  = v64;
  // layer-2 f32 aliases
  float* h32    = (float*)(ws + 201326592);    // D: f32 dup of layer-1 output (obuf dead)
  float* qk32   = (float*)(ws + 134217728);    // C0
  float* v32    = (float*)(ws + 167772160);    // C1
  float* obuf32 = (float*)(ws + 67108864);     // B0 (qk64 dead after bucket_sort)
  float* comb32 = (float*)(ws + 100663296);    // B1
  float* ao32   = (float*)(ws + 134217728);    // C0 (qk32 dead after attn)
  float* hA32   = (float*)(ws + 167772160);    // C1 (v32 dead)
  float* hid32  = (float*)(ws + 67108864);     // B0 (obuf32 dead) 2048x2048 f32
  float* y32    = (float*)(ws + 100663296);    // B1 (comb32 dead)
  float* h2f    = (float*)(ws + 201326592);    // D  (h32 dead after v2 gemm)
  float* hf32   = (float*)(ws + 134217728);    // C0 (ao32 dead)

  embed_kernel<<<16384, 256, 0, stream>>>(x_enc, x_mark_enc, x_dec, x_mark_dec,
                                          conv_w, mark_w, h64);

  // ================= layer 0 : full fp64 (round-2 proven) =================
  dgemm_kernel<<<dim3(256,8), 256, 0, stream>>>(h64, qk_w, nullptr, qk64, nullptr,
                                                512, 512, 4);
  dgemm_kernel<<<dim3(256,8), 256, 0, stream>>>(h64, v_w, nullptr, v64, nullptr,
                                                512, 512, 4);
  bucket_sort_kernel<<<512, 256, 0, stream>>>(qk64, rotations, stick);
  for (int g = 0; g < 8; ++g) {
    lsh_attn_kernel<<<2048, 256, 0, stream>>>(qk64, v64, stick, obuf, lse64, g*16);
    combine_kernel<<<4096, 256, 0, stream>>>(obuf, lse64, comb, g*16);
  }
  dgemm_kernel<<<dim3(256,8), 256, 0, stream>>>(comb, out_w, out_b, qk64, nullptr,
                                                512, 512, 1);
  ln_kernel<<<16384, 256, 0, stream>>>(h64, qk64, ln1_g, ln1_b, h64, nullptr);
  for (int c = 0; c < 8; ++c) {
    dgemm_kernel<<<dim3(32,32), 256, 0, stream>>>(h64 + (size_t)c*2048*512, ffn_w1,
                                                  ffn_b1, qk64, nullptr, 2048, 512, 3);
    dgemm_kernel<<<dim3(32,8), 256, 0, stream>>>(qk64, ffn_w2, ffn_b2,
                                                 comb + (size_t)c*2048*512, nullptr,
                                                 512, 2048, 1);
  }
  ln_kernel<<<16384, 256, 0, stream>>>(h64, comb, ln2_g, ln2_b, h64, h32);

  // ================= layer 1 : f64 decisions, f32 values =================
  sgemm_kernel<<<dim3(128,4), 256, 0, stream>>>(h32, v_w + 262144, nullptr, v32,
                                                512, 512, 4);
  dgemm_kernel<<<dim3(256,8), 256, 0, stream>>>(h64, qk_w + 262144, nullptr, qk64, qk32,
                                                512, 512, 4 | 8);
  bucket_sort_kernel<<<512, 256, 0, stream>>>(qk64, rotations + 4096, stick);
  for (int g = 0; g < 4; ++g) {
    lsh_attn32_kernel<<<4096, 256, 0, stream>>>(qk32, v32, stick, obuf32, lse32, g*32);
    combine32_kernel<<<8192, 256, 0, stream>>>(obuf32, lse32, comb32, g*32);
  }
  sgemm_kernel<<<dim3(128,4), 256, 0, stream>>>(comb32, out_w + 262144, out_b + 512,
                                                ao32, 512, 512, 1);
  lnmx_kernel<<<16384, 256, 0, stream>>>(h64, ao32, ln1_g + 512, ln1_b + 512, hA32);
  for (int c = 0; c < 8; ++c) {
    sgemm_kernel<<<dim3(16,16), 256, 0, stream>>>(hA32 + (size_t)c*2048*512,
                                                  ffn_w1 + 1048576, ffn_b1 + 2048,
                                                  hid32, 2048, 512, 3);
    sgemm_kernel<<<dim3(16,4), 256, 0, stream>>>(hid32, ffn_w2 + 1048576, ffn_b2 + 512,
                                                 y32 + (size_t)c*2048*512, 512, 2048, 1);
  }
  ln32_kernel<<<16384, 256, 0, stream>>>(hA32, y32, ln2_g + 512, ln2_b + 512, h2f);
  ln32_kernel<<<16384, 256, 0, stream>>>(h2f, nullptr, lnf_g, lnf_b, hf32);
  proj_kernel<<<4096, 64, 0, stream>>>(hf32, proj_w, proj_b, (float*)d_out);
}

// Round 6
// 6219.511 us; speedup vs baseline: 1.6076x; 1.6076x over previous
//
#include <hip/hip_runtime.h>
#include <math.h>

#define T_ 1024
#define NT_ 4096
#define MASKSELF64 -50000.0
#define MASKSELF32 -50000.0f

// ---------------- embedding (fp64) ----------------
__global__ __launch_bounds__(256)
void embed_kernel(const float* __restrict__ x_enc, const float* __restrict__ x_mark_enc,
                  const float* __restrict__ x_dec, const float* __restrict__ x_mark_dec,
                  const float* __restrict__ conv_w, const float* __restrict__ mark_w,
                  double* __restrict__ h) {
  int bt = blockIdx.x;
  int b = bt >> 10, t = bt & 1023;
  __shared__ double xs[3][7];
  __shared__ double xm[4];
  int tid = threadIdx.x;
  if (tid < 21) {
    int k = tid / 7, i = tid % 7;
    int tt = t + k - 1;
    if (tt < 0) tt += 1024;
    if (tt >= 1024) tt -= 1024;
    xs[k][i] = (double)((tt < 768) ? x_enc[((size_t)b*768 + tt)*7 + i]
                                   : x_dec[((size_t)b*512 + (tt - 512))*7 + i]);
  }
  if (tid >= 32 && tid < 36) {
    int m = tid - 32;
    xm[m] = (double)((t < 768) ? x_mark_enc[((size_t)b*768 + t)*4 + m]
                               : x_mark_dec[((size_t)b*512 + (t - 512))*4 + m]);
  }
  __syncthreads();
  for (int o = tid; o < 512; o += 256) {
    double acc = 0.0;
    #pragma unroll
    for (int k = 0; k < 3; ++k)
      #pragma unroll
      for (int i = 0; i < 7; ++i)
        acc += xs[k][i] * (double)conv_w[(o*7 + i)*3 + k];
    #pragma unroll
    for (int m = 0; m < 4; ++m) acc += xm[m] * (double)mark_w[m*512 + o];
    int j2 = o & ~1;
    double dv = exp((double)j2 * (-9.210340371976184 / 512.0));
    double arg = (double)t * dv;
    acc += (o & 1) ? cos(arg) : sin(arg);
    h[((size_t)b*1024 + t)*512 + o] = acc;
  }
}

// ---------------- fp64 scalar GEMM 64x64x16, 4x4 microtile (R2/R5-proven numerics) ----------------
// ldb = B row stride (for weight column slices); N = C row stride.
// flags: 1=+bias, 2=gelu(exact), 4=qkv layout, 8=dup f32 store (qkv only), 16=accumulate into C
__global__ __launch_bounds__(256)
void dgemm_kernel(const double* __restrict__ A, const float* __restrict__ Bm,
                  const float* __restrict__ bias, double* __restrict__ C,
                  float* __restrict__ C32, int N, int K, int ldb, int flags) {
  __shared__ double As[16][65];
  __shared__ double Bs[16][66];
  int tid = threadIdx.x;
  int tx = tid & 15, ty = tid >> 4;
  int arow = blockIdx.x * 64;
  int bcol = blockIdx.y * 64;
  double acc[4][4];
  #pragma unroll
  for (int i=0;i<4;++i)
    #pragma unroll
    for (int j=0;j<4;++j) acc[i][j]=0.0;
  for (int k0 = 0; k0 < K; k0 += 16) {
    #pragma unroll
    for (int q = 0; q < 2; ++q) {
      int e = tid*2 + q;
      int r = e >> 3, c2 = (e & 7)*2;
      double2 av = *(const double2*)(A + (size_t)(arow + r)*K + k0 + c2);
      As[c2][r] = av.x; As[c2+1][r] = av.y;
      int kk = e >> 5, cc = (e & 31)*2;
      float2 bv = *(const float2*)(Bm + (size_t)(k0+kk)*ldb + bcol + cc);
      Bs[kk][cc] = (double)bv.x; Bs[kk][cc+1] = (double)bv.y;
    }
    __syncthreads();
    #pragma unroll
    for (int kk=0;kk<16;++kk) {
      double a[4], bb[4];
      #pragma unroll
      for (int i=0;i<4;++i) a[i] = As[kk][ty + 16*i];
      #pragma unroll
      for (int j=0;j<4;++j) bb[j] = Bs[kk][tx + 16*j];
      #pragma unroll
      for (int i=0;i<4;++i)
        #pragma unroll
        for (int j=0;j<4;++j) acc[i][j] += a[i]*bb[j];
    }
    __syncthreads();
  }
  #pragma unroll
  for (int i=0;i<4;++i) {
    int row = arow + ty + 16*i;
    #pragma unroll
    for (int j=0;j<4;++j) {
      int col = bcol + tx + 16*j;
      double cv = acc[i][j];
      if (flags & 1) cv += (double)bias[col];
      if (flags & 2) cv = 0.5*cv*(1.0 + erf(cv*0.70710678118654752440));
      if (flags & 4) {
        int b = row >> 10, t = row & 1023;
        int hd = col >> 6, dd = col & 63;
        size_t idx = (((size_t)b*8 + hd)*1024 + t)*64 + dd;
        C[idx] = cv;
        if (flags & 8) C32[idx] = (float)cv;
      } else {
        size_t idx = (size_t)row*N + col;
        if (flags & 16) cv += C[idx];
        C[idx] = cv;
      }
    }
  }
}

// ---------------- fp32 GEMM 128x128x16, 8x8 microtile (conflict-free remap) ----------------
// flags: 1=+bias, 2=gelu(exact), 4=qkv layout
__global__ __launch_bounds__(256)
void sgemm_kernel(const float* __restrict__ A, const float* __restrict__ Bm,
                  const float* __restrict__ bias, float* __restrict__ C,
                  int N, int K, int flags) {
  __shared__ float As[16][128];
  __shared__ float Bs[16][128];
  int tid = threadIdx.x;
  int tx = tid & 15, ty = tid >> 4;
  float acc[8][8];
  #pragma unroll
  for (int i=0;i<8;++i)
    #pragma unroll
    for (int j=0;j<8;++j) acc[i][j]=0.f;
  const int arow = blockIdx.x*128;
  const int bcol = blockIdx.y*128;
  for (int k0 = 0; k0 < K; k0 += 16) {
    #pragma unroll
    for (int q = 0; q < 2; ++q) {
      int f4 = tid*2 + q;
      int r = f4 >> 2, c4 = f4 & 3;
      float4 av = *(const float4*)(A + (size_t)(arow + r)*K + k0 + c4*4);
      As[c4*4+0][r]=av.x; As[c4*4+1][r]=av.y; As[c4*4+2][r]=av.z; As[c4*4+3][r]=av.w;
      int kk = f4 >> 5, cc = f4 & 31;
      *(float4*)&Bs[kk][cc*4] = *(const float4*)(Bm + (size_t)(k0+kk)*N + bcol + cc*4);
    }
    __syncthreads();
    #pragma unroll
    for (int kk=0;kk<16;++kk) {
      float a[8], bb[8];
      #pragma unroll
      for (int i=0;i<8;++i) a[i] = As[kk][ty + 16*i];
      #pragma unroll
      for (int j=0;j<8;++j) bb[j] = Bs[kk][tx + 16*j];
      #pragma unroll
      for (int i=0;i<8;++i)
        #pragma unroll
        for (int j=0;j<8;++j) acc[i][j] += a[i]*bb[j];
    }
    __syncthreads();
  }
  #pragma unroll
  for (int i=0;i<8;++i) {
    int row = arow + ty + 16*i;
    #pragma unroll
    for (int j=0;j<8;++j) {
      int col = bcol + tx + 16*j;
      float cv = acc[i][j];
      if (flags & 1) cv += bias[col];
      if (flags & 2) cv = 0.5f*cv*(1.0f + erff(cv*0.70710678118654752f));
      if (flags & 4) {
        int b = row >> 10, t = row & 1023;
        int hd = col >> 6, dd = col & 63;
        C[(((size_t)b*8 + hd)*1024 + t)*64 + dd] = cv;
      } else {
        C[(size_t)row*N + col] = cv;
      }
    }
  }
}

// ---------------- LSH bucket assignment + per-round counting sort (fp64) ----------------
__global__ __launch_bounds__(256)
void bucket_sort_kernel(const double* __restrict__ qk, const float* __restrict__ rot,
                        int* __restrict__ sticker) {
  int bh = blockIdx.x >> 2, r = blockIdx.x & 3;
  __shared__ double rots[64][17];
  __shared__ unsigned char bucket[1024];
  __shared__ int cnt[32];
  __shared__ int off[32];
  int tid = threadIdx.x;
  for (int idx = tid; idx < 1024; idx += 256) {
    int f = idx >> 4, i = idx & 15;
    rots[f][i] = (double)rot[(f*4 + r)*16 + i];
  }
  if (tid < 32) cnt[tid] = 0;
  __syncthreads();
  for (int t = tid; t < 1024; t += 256) {
    const double* q = qk + ((size_t)bh*1024 + t)*64;
    double rv[16];
    #pragma unroll
    for (int i=0;i<16;++i) rv[i]=0.0;
    for (int f=0; f<64; ++f) {
      double qf = q[f];
      #pragma unroll
      for (int i=0;i<16;++i) rv[i] += qf * rots[f][i];
    }
    int best = 0; double bv = rv[0];
    #pragma unroll
    for (int i=1;i<16;++i) if (rv[i] > bv) { bv=rv[i]; best=i; }
    #pragma unroll
    for (int i=0;i<16;++i) { double nv = -rv[i]; if (nv > bv) { bv=nv; best=16+i; } }
    bucket[t] = (unsigned char)best;
    atomicAdd(&cnt[best], 1);
  }
  __syncthreads();
  if (tid == 0) {
    int s = 0;
    for (int k=0;k<32;++k) { off[k]=s; s+=cnt[k]; }
  }
  __syncthreads();
  if (tid < 32) {
    int pos = off[tid];
    int* outp = sticker + (size_t)bh*NT_ + r*1024;
    for (int t=0;t<1024;++t)
      if (bucket[t] == (unsigned char)tid) outp[pos++] = t;
  }
}

// ---------------- chunked LSH attention fp64 ----------------
__global__ __launch_bounds__(256)
void lsh_attn_kernel(const double* __restrict__ qk, const double* __restrict__ v,
                     const int* __restrict__ sticker,
                     double* __restrict__ obuf, double* __restrict__ lse, int bh0) {
  int bh_l = blockIdx.x >> 7;
  int bh = bh0 + bh_l;
  int c  = blockIdx.x & 127;
  int cprev = (c + 127) & 127;
  __shared__ double kv[64][66];
  __shared__ double pp[32][66];
  __shared__ double rnorm[64];
  __shared__ int tk[64];
  int tid = threadIdx.x;
  if (tid < 64) {
    int chunk = (tid < 32) ? c : cprev;
    tk[tid] = sticker[(size_t)bh*NT_ + chunk*32 + (tid & 31)];
  }
  __syncthreads();
  for (int idx = tid; idx < 2048; idx += 256) {
    int j = idx >> 5, c2 = (idx & 31)*2;
    *(double2*)&kv[j][c2] = *(const double2*)(qk + ((size_t)bh*1024 + tk[j])*64 + c2);
  }
  __syncthreads();
  if (tid < 64) {
    double s = 0.0;
    #pragma unroll
    for (int f=0; f<64; ++f) { double x = kv[tid][f]; s += x*x; }
    rnorm[tid] = 1.0 / fmax(sqrt(s), 1e-12);
  }
  __syncthreads();
  int i = tid >> 3, sub = tid & 7;
  int ti = tk[i];
  double dots[8];
  double dmax = -1.0e300;
  #pragma unroll
  for (int jj=0; jj<8; ++jj) {
    int j = sub*8 + jj;
    double s = 0.0;
    #pragma unroll
    for (int f=0; f<64; ++f) s += kv[i][f] * kv[j][f];
    s *= rnorm[j] * 0.125;
    if (ti == tk[j]) s = MASKSELF64;
    dots[jj] = s;
    dmax = fmax(dmax, s);
  }
  #pragma unroll
  for (int w=1; w<8; w<<=1) dmax = fmax(dmax, __shfl_xor(dmax, w, 64));
  double esum = 0.0;
  #pragma unroll
  for (int jj=0; jj<8; ++jj) {
    double e = exp(dots[jj] - dmax);
    esum += e;
    pp[i][sub*8+jj] = e;
  }
  #pragma unroll
  for (int w=1; w<8; w<<=1) esum += __shfl_xor(esum, w, 64);
  __syncthreads();
  for (int idx = tid; idx < 2048; idx += 256) {
    int j = idx >> 5, c2 = (idx & 31)*2;
    *(double2*)&kv[j][c2] = *(const double2*)(v + ((size_t)bh*1024 + tk[j])*64 + c2);
  }
  __syncthreads();
  double ov[8];
  #pragma unroll
  for (int dd=0;dd<8;++dd) ov[dd]=0.0;
  for (int j=0;j<64;++j) {
    double p = pp[i][j];
    #pragma unroll
    for (int dd=0;dd<8;++dd) ov[dd] += p * kv[j][sub*8+dd];
  }
  double rinv = 1.0 / esum;
  int r = c >> 5;
  size_t ob = (((size_t)bh_l*4 + r)*1024 + ti)*64 + sub*8;
  #pragma unroll
  for (int dd=0;dd<8;++dd) obuf[ob + dd] = ov[dd]*rinv;
  if (sub == 0) lse[((size_t)bh*4 + r)*1024 + ti] = log(esum) + dmax;
}

// ---------------- combine rounds (fp64) ----------------
__global__ __launch_bounds__(256)
void combine_kernel(const double* __restrict__ obuf, const double* __restrict__ lse,
                    double* __restrict__ comb, int bh0) {
  int g = blockIdx.x*4 + (threadIdx.x >> 6);
  int bh_l = g >> 10, t = g & 1023;
  int bh = bh0 + bh_l;
  int d = threadIdx.x & 63;
  double l[4];
  #pragma unroll
  for (int r=0;r<4;++r) l[r] = lse[((size_t)bh*4 + r)*1024 + t];
  double m = fmax(fmax(l[0],l[1]), fmax(l[2],l[3]));
  double e[4], s=0.0;
  #pragma unroll
  for (int r=0;r<4;++r){ e[r]=exp(l[r]-m); s+=e[r]; }
  double rs = 1.0/s;
  double o = 0.0;
  #pragma unroll
  for (int r=0;r<4;++r)
    o += e[r]*rs * obuf[(((size_t)bh_l*4 + r)*1024 + t)*64 + d];
  int b = bh >> 3, hd = bh & 7;
  comb[((size_t)b*1024 + t)*512 + hd*64 + d] = o;
}

// ---------------- chunked LSH attention fp32 (layer-2 value path) ----------------
__global__ __launch_bounds__(256)
void lsh_attn32_kernel(const float* __restrict__ qk, const float* __restrict__ v,
                       const int* __restrict__ sticker,
                       float* __restrict__ obuf, float* __restrict__ lse, int bh0) {
  int bh_l = blockIdx.x >> 7;
  int bh = bh0 + bh_l;
  int c  = blockIdx.x & 127;
  int cprev = (c + 127) & 127;
  __shared__ float kv[64][68];
  __shared__ float pp[32][68];
  __shared__ float rnorm[64];
  __shared__ int tk[64];
  int tid = threadIdx.x;
  if (tid < 64) {
    int chunk = (tid < 32) ? c : cprev;
    tk[tid] = sticker[(size_t)bh*NT_ + chunk*32 + (tid & 31)];
  }
  __syncthreads();
  for (int idx = tid; idx < 1024; idx += 256) {
    int j = idx >> 4, c4 = (idx & 15)*4;
    *(float4*)&kv[j][c4] = *(const float4*)(qk + ((size_t)bh*1024 + tk[j])*64 + c4);
  }
  __syncthreads();
  if (tid < 64) {
    float s = 0.f;
    #pragma unroll
    for (int f=0; f<64; ++f) { float x = kv[tid][f]; s += x*x; }
    rnorm[tid] = 1.0f / fmaxf(sqrtf(s), 1e-12f);
  }
  __syncthreads();
  int i = tid >> 3, sub = tid & 7;
  int ti = tk[i];
  float dots[8];
  float dmax = -1.0e30f;
  #pragma unroll
  for (int jj=0; jj<8; ++jj) {
    int j = sub*8 + jj;
    float s = 0.f;
    #pragma unroll
    for (int f=0; f<64; ++f) s += kv[i][f] * kv[j][f];
    s *= rnorm[j] * 0.125f;
    if (ti == tk[j]) s = MASKSELF32;
    dots[jj] = s;
    dmax = fmaxf(dmax, s);
  }
  #pragma unroll
  for (int w=1; w<8; w<<=1) dmax = fmaxf(dmax, __shfl_xor(dmax, w, 64));
  float esum = 0.f;
  #pragma unroll
  for (int jj=0; jj<8; ++jj) {
    float e = expf(dots[jj] - dmax);
    esum += e;
    pp[i][sub*8+jj] = e;
  }
  #pragma unroll
  for (int w=1; w<8; w<<=1) esum += __shfl_xor(esum, w, 64);
  __syncthreads();
  for (int idx = tid; idx < 1024; idx += 256) {
    int j = idx >> 4, c4 = (idx & 15)*4;
    *(float4*)&kv[j][c4] = *(const float4*)(v + ((size_t)bh*1024 + tk[j])*64 + c4);
  }
  __syncthreads();
  float ov[8];
  #pragma unroll
  for (int dd=0;dd<8;++dd) ov[dd]=0.f;
  for (int j=0;j<64;++j) {
    float p = pp[i][j];
    #pragma unroll
    for (int dd=0;dd<8;++dd) ov[dd] += p * kv[j][sub*8+dd];
  }
  float rinv = 1.0f / esum;
  int r = c >> 5;
  size_t ob = (((size_t)bh_l*4 + r)*1024 + ti)*64 + sub*8;
  #pragma unroll
  for (int dd=0;dd<8;++dd) obuf[ob + dd] = ov[dd]*rinv;
  if (sub == 0) lse[((size_t)bh*4 + r)*1024 + ti] = logf(esum) + dmax;
}

// ---------------- combine rounds (fp32) ----------------
__global__ __launch_bounds__(256)
void combine32_kernel(const float* __restrict__ obuf, const float* __restrict__ lse,
                      float* __restrict__ comb, int bh0) {
  int g = blockIdx.x*4 + (threadIdx.x >> 6);
  int bh_l = g >> 10, t = g & 1023;
  int bh = bh0 + bh_l;
  int d = threadIdx.x & 63;
  float l[4];
  #pragma unroll
  for (int r=0;r<4;++r) l[r] = lse[((size_t)bh*4 + r)*1024 + t];
  float m = fmaxf(fmaxf(l[0],l[1]), fmaxf(l[2],l[3]));
  float e[4], s=0.f;
  #pragma unroll
  for (int r=0;r<4;++r){ e[r]=expf(l[r]-m); s+=e[r]; }
  float rs = 1.0f/s;
  float o = 0.f;
  #pragma unroll
  for (int r=0;r<4;++r)
    o += e[r]*rs * obuf[(((size_t)bh_l*4 + r)*1024 + t)*64 + d];
  int b = bh >> 3, hd = bh & 7;
  comb[((size_t)b*1024 + t)*512 + hd*64 + d] = o;
}

// ---------------- layernorm fp64 (optional residual, optional f32 dup) ----------------
__global__ __launch_bounds__(256)
void ln_kernel(const double* __restrict__ x, const double* __restrict__ res,
               const float* __restrict__ gw, const float* __restrict__ bw,
               double* __restrict__ outp, float* __restrict__ out32) {
  int row = blockIdx.x;
  int tid = threadIdx.x;
  const double* xr = x + (size_t)row*512;
  double v0 = xr[tid], v1 = xr[tid+256];
  if (res) { const double* rr = res + (size_t)row*512; v0 += rr[tid]; v1 += rr[tid+256]; }
  double s = v0 + v1;
  #pragma unroll
  for (int w=1; w<64; w<<=1) s += __shfl_xor(s, w, 64);
  __shared__ double red[4];
  int wid = tid >> 6, lane = tid & 63;
  if (lane == 0) red[wid] = s;
  __syncthreads();
  s = red[0]+red[1]+red[2]+red[3];
  double m = s * (1.0/512.0);
  double d0 = v0 - m, d1 = v1 - m;
  double q = d0*d0 + d1*d1;
  #pragma unroll
  for (int w=1; w<64; w<<=1) q += __shfl_xor(q, w, 64);
  __syncthreads();
  if (lane == 0) red[wid] = q;
  __syncthreads();
  q = red[0]+red[1]+red[2]+red[3];
  double var = q * (1.0/512.0);
  double rstd = 1.0 / sqrt(var + 1e-5);
  double o0 = d0*rstd*(double)gw[tid] + (double)bw[tid];
  double o1 = d1*rstd*(double)gw[tid+256] + (double)bw[tid+256];
  outp[(size_t)row*512 + tid]       = o0;
  outp[(size_t)row*512 + tid + 256] = o1;
  if (out32) {
    out32[(size_t)row*512 + tid]       = (float)o0;
    out32[(size_t)row*512 + tid + 256] = (float)o1;
  }
}

// ---------------- layernorm: x f64 + res f32 -> f32 ----------------
__global__ __launch_bounds__(256)
void lnmx_kernel(const double* __restrict__ x, const float* __restrict__ res,
                 const float* __restrict__ gw, const float* __restrict__ bw,
                 float* __restrict__ out32) {
  int row = blockIdx.x;
  int tid = threadIdx.x;
  const double* xr = x + (size_t)row*512;
  const float*  rr = res + (size_t)row*512;
  double v0 = xr[tid] + (double)rr[tid];
  double v1 = xr[tid+256] + (double)rr[tid+256];
  double s = v0 + v1;
  #pragma unroll
  for (int w=1; w<64; w<<=1) s += __shfl_xor(s, w, 64);
  __shared__ double red[4];
  int wid = tid >> 6, lane = tid & 63;
  if (lane == 0) red[wid] = s;
  __syncthreads();
  s = red[0]+red[1]+red[2]+red[3];
  double m = s * (1.0/512.0);
  double d0 = v0 - m, d1 = v1 - m;
  double q = d0*d0 + d1*d1;
  #pragma unroll
  for (int w=1; w<64; w<<=1) q += __shfl_xor(q, w, 64);
  __syncthreads();
  if (lane == 0) red[wid] = q;
  __syncthreads();
  q = red[0]+red[1]+red[2]+red[3];
  double rstd = 1.0 / sqrt(q * (1.0/512.0) + 1e-5);
  out32[(size_t)row*512 + tid]       = (float)(d0*rstd*(double)gw[tid] + (double)bw[tid]);
  out32[(size_t)row*512 + tid + 256] = (float)(d1*rstd*(double)gw[tid+256] + (double)bw[tid+256]);
}

// ---------------- layernorm f32 in/out (double stats), optional residual ----------------
__global__ __launch_bounds__(256)
void ln32_kernel(const float* __restrict__ x, const float* __restrict__ res,
                 const float* __restrict__ gw, const float* __restrict__ bw,
                 float* __restrict__ out32) {
  int row = blockIdx.x;
  int tid = threadIdx.x;
  const float* xr = x + (size_t)row*512;
  double v0 = (double)xr[tid], v1 = (double)xr[tid+256];
  if (res) { const float* rr = res + (size_t)row*512; v0 += (double)rr[tid]; v1 += (double)rr[tid+256]; }
  double s = v0 + v1;
  #pragma unroll
  for (int w=1; w<64; w<<=1) s += __shfl_xor(s, w, 64);
  __shared__ double red[4];
  int wid = tid >> 6, lane = tid & 63;
  if (lane == 0) red[wid] = s;
  __syncthreads();
  s = red[0]+red[1]+red[2]+red[3];
  double m = s * (1.0/512.0);
  double d0 = v0 - m, d1 = v1 - m;
  double q = d0*d0 + d1*d1;
  #pragma unroll
  for (int w=1; w<64; w<<=1) q += __shfl_xor(q, w, 64);
  __syncthreads();
  if (lane == 0) red[wid] = q;
  __syncthreads();
  q = red[0]+red[1]+red[2]+red[3];
  double rstd = 1.0 / sqrt(q * (1.0/512.0) + 1e-5);
  out32[(size_t)row*512 + tid]       = (float)(d0*rstd*(double)gw[tid] + (double)bw[tid]);
  out32[(size_t)row*512 + tid + 256] = (float)(d1*rstd*(double)gw[tid+256] + (double)bw[tid+256]);
}

// ---------------- final projection (f32 input, f64 accum, f32 store) ----------------
__global__ __launch_bounds__(64)
void proj_kernel(const float* __restrict__ hf, const float* __restrict__ pw,
                 const float* __restrict__ pb, float* __restrict__ outp) {
  int row = blockIdx.x;
  int b = row >> 8, tp = row & 255;
  const float* hr = hf + ((size_t)b*1024 + 768 + tp)*512;
  int lane = threadIdx.x;
  double acc[7];
  #pragma unroll
  for (int cc=0;cc<7;++cc) acc[cc]=0.0;
  for (int d = lane; d < 512; d += 64) {
    double hv = (double)hr[d];
    #pragma unroll
    for (int cc=0;cc<7;++cc) acc[cc] += hv * (double)pw[d*7 + cc];
  }
  #pragma unroll
  for (int cc=0;cc<7;++cc) {
    double s = acc[cc];
    #pragma unroll
    for (int w=32;w>=1;w>>=1) s += __shfl_xor(s, w, 64);
    if (lane == 0) outp[(size_t)row*7 + cc] = (float)(s + (double)pb[cc]);
  }
}

extern "C" void kernel_launch(void* const* d_in, const int* in_sizes, int n_in,
                              void* d_out, int out_size, void* d_ws, size_t ws_size,
                              hipStream_t stream) {
  (void)in_sizes; (void)n_in; (void)out_size; (void)ws_size;
  const float* x_enc      = (const float*)d_in[0];
  const float* x_mark_enc = (const float*)d_in[1];
  const float* x_dec      = (const float*)d_in[2];
  const float* x_mark_dec = (const float*)d_in[3];
  const float* conv_w     = (const float*)d_in[4];
  const float* mark_w     = (const float*)d_in[5];
  const float* qk_w       = (const float*)d_in[6];
  const float* v_w        = (const float*)d_in[7];
  const float* out_w      = (const float*)d_in[8];
  const float* out_b      = (const float*)d_in[9];
  const float* ln1_g      = (const float*)d_in[10];
  const float* ln1_b      = (const float*)d_in[11];
  const float* ln2_g      = (const float*)d_in[12];
  const float* ln2_b      = (const float*)d_in[13];
  const float* ffn_w1     = (const float*)d_in[14];
  const float* ffn_b1     = (const float*)d_in[15];
  const float* ffn_w2     = (const float*)d_in[16];
  const float* ffn_b2     = (const float*)d_in[17];
  const float* lnf_g      = (const float*)d_in[18];
  const float* lnf_b      = (const float*)d_in[19];
  const float* proj_w     = (const float*)d_in[20];
  const float* proj_b     = (const float*)d_in[21];
  const float* rotations  = (const float*)d_in[22];

  char* ws = (char*)d_ws;
  // regions: A [0,64M) B [64,128M) C [128,192M) D [192,224M)
  double* h64   = (double*)(ws);               // A
  double* qk64  = (double*)(ws + 67108864);    // B: qk64 / ffn1 hidden slice
  double* v64   = (double*)(ws + 134217728);   // C: v64 / comb / ffn2 accumulator
  double* obuf  = (double*)(ws + 201326592);   // D: o_rounds (16 bh)
  int*    stick = (int*)   (ws + 234881024);   // [224,226M)
  double* lse64 = (double*)(ws + 236978176);   // [226,230M)
  float*  lse32 = (float*) (ws + 236978176);
  double* comb  = v64;
  // layer-2 f32 aliases
  float* h32    = (float*)(ws + 201326592);    // D    (obuf dead after layer-1 attn)
  float* qk32   = (float*)(ws + 134217728);    // C0 [128,160)
  float* v32    = (float*)(ws + 167772160);    // C1 [160,192)
  float* obuf32 = (float*)(ws + 67108864);     // B0 [64,96)   (qk64 dead after bucket_sort)
  float* comb32 = (float*)(ws + 100663296);    // B1 [96,128)
  float* ao32   = (float*)(ws + 201326592);    // D   (h32 dead after v-GEMM)
  float* hA32   = (float*)(ws + 134217728);    // C0  (qk32 dead after attn)
  float* hid32  = (float*)(ws);                // A+B [0,128M) full f32 hidden (h64,obuf32,comb32 dead)
  float* y32    = (float*)(ws + 167772160);    // C1  (v32 dead)
  float* h2f    = (float*)(ws + 201326592);    // D   (ao32 dead)
  float* hf32   = (float*)(ws);                // A0 [0,32M) (hid32 dead)

  embed_kernel<<<16384, 256, 0, stream>>>(x_enc, x_mark_enc, x_dec, x_mark_dec,
                                          conv_w, mark_w, h64);

  // ================= layer 0 : full fp64, all GEMMs dim3(256,8)=2048 blocks =================
  dgemm_kernel<<<dim3(256,8), 256, 0, stream>>>(h64, qk_w, nullptr, qk64, nullptr,
                                                512, 512, 512, 4);
  dgemm_kernel<<<dim3(256,8), 256, 0, stream>>>(h64, v_w, nullptr, v64, nullptr,
                                                512, 512, 512, 4);
  bucket_sort_kernel<<<512, 256, 0, stream>>>(qk64, rotations, stick);
  for (int g = 0; g < 8; ++g) {
    lsh_attn_kernel<<<2048, 256, 0, stream>>>(qk64, v64, stick, obuf, lse64, g*16);
    combine_kernel<<<4096, 256, 0, stream>>>(obuf, lse64, comb, g*16);
  }
  dgemm_kernel<<<dim3(256,8), 256, 0, stream>>>(comb, out_w, out_b, qk64, nullptr,
                                                512, 512, 512, 1);
  ln_kernel<<<16384, 256, 0, stream>>>(h64, qk64, ln1_g, ln1_b, h64, nullptr);
  for (int c = 0; c < 4; ++c) {   // FFN col-chunked: hidden slice [16384][512] f64 in qk64
    dgemm_kernel<<<dim3(256,8), 256, 0, stream>>>(h64, ffn_w1 + c*512,
                                                  ffn_b1 + c*512, qk64, nullptr,
                                                  512, 512, 2048, 3);
    dgemm_kernel<<<dim3(256,8), 256, 0, stream>>>(qk64, ffn_w2 + (size_t)c*512*512,
                                                  ffn_b2, comb, nullptr,
                                                  512, 512, 512, (c == 0) ? 1 : 16);
  }
  ln_kernel<<<16384, 256, 0, stream>>>(h64, comb, ln2_g, ln2_b, h64, h32);

  // ================= layer 1 : f64 decisions, f32 values =================
  sgemm_kernel<<<dim3(128,4), 256, 0, stream>>>(h32, v_w + 262144, nullptr, v32,
                                                512, 512, 4);
  dgemm_kernel<<<dim3(256,8), 256, 0, stream>>>(h64, qk_w + 262144, nullptr, qk64, qk32,
                                                512, 512, 512, 4 | 8);
  bucket_sort_kernel<<<512, 256, 0, stream>>>(qk64, rotations + 4096, stick);
  for (int g = 0; g < 4; ++g) {
    lsh_attn32_kernel<<<4096, 256, 0, stream>>>(qk32, v32, stick, obuf32, lse32, g*32);
    combine32_kernel<<<8192, 256, 0, stream>>>(obuf32, lse32, comb32, g*32);
  }
  sgemm_kernel<<<dim3(128,4), 256, 0, stream>>>(comb32, out_w + 262144, out_b + 512,
                                                ao32, 512, 512, 1);
  lnmx_kernel<<<16384, 256, 0, stream>>>(h64, ao32, ln1_g + 512, ln1_b + 512, hA32);
  // FFN full-size f32: hidden [16384][2048] at [0,128M)
  sgemm_kernel<<<dim3(128,16), 256, 0, stream>>>(hA32, ffn_w1 + 1048576, ffn_b1 + 2048,
                                                 hid32, 2048, 512, 3);
  sgemm_kernel<<<dim3(128,4), 256, 0, stream>>>(hid32, ffn_w2 + 1048576, ffn_b2 + 512,
                                                y32, 512, 2048, 1);
  ln32_kernel<<<16384, 256, 0, stream>>>(hA32, y32, ln2_g + 512, ln2_b + 512, h2f);
  ln32_kernel<<<16384, 256, 0, stream>>>(h2f, nullptr, lnf_g, lnf_b, hf32);
  proj_kernel<<<4096, 64, 0, stream>>>(hf32, proj_w, proj_b, (float*)d_out);
}

// Round 7
// 5733.244 us; speedup vs baseline: 1.7440x; 1.0848x over previous
//
#include <hip/hip_runtime.h>
#include <math.h>

#define T_ 1024
#define NT_ 4096
#define MASKSELF64 -50000.0
#define MASKSELF32 -50000.0f

// ---------------- embedding (fp64) ----------------
__global__ __launch_bounds__(256)
void embed_kernel(const float* __restrict__ x_enc, const float* __restrict__ x_mark_enc,
                  const float* __restrict__ x_dec, const float* __restrict__ x_mark_dec,
                  const float* __restrict__ conv_w, const float* __restrict__ mark_w,
                  double* __restrict__ h) {
  int bt = blockIdx.x;
  int b = bt >> 10, t = bt & 1023;
  __shared__ double xs[3][7];
  __shared__ double xm[4];
  int tid = threadIdx.x;
  if (tid < 21) {
    int k = tid / 7, i = tid % 7;
    int tt = t + k - 1;
    if (tt < 0) tt += 1024;
    if (tt >= 1024) tt -= 1024;
    xs[k][i] = (double)((tt < 768) ? x_enc[((size_t)b*768 + tt)*7 + i]
                                   : x_dec[((size_t)b*512 + (tt - 512))*7 + i]);
  }
  if (tid >= 32 && tid < 36) {
    int m = tid - 32;
    xm[m] = (double)((t < 768) ? x_mark_enc[((size_t)b*768 + t)*4 + m]
                               : x_mark_dec[((size_t)b*512 + (t - 512))*4 + m]);
  }
  __syncthreads();
  for (int o = tid; o < 512; o += 256) {
    double acc = 0.0;
    #pragma unroll
    for (int k = 0; k < 3; ++k)
      #pragma unroll
      for (int i = 0; i < 7; ++i)
        acc += xs[k][i] * (double)conv_w[(o*7 + i)*3 + k];
    #pragma unroll
    for (int m = 0; m < 4; ++m) acc += xm[m] * (double)mark_w[m*512 + o];
    int j2 = o & ~1;
    double dv = exp((double)j2 * (-9.210340371976184 / 512.0));
    double arg = (double)t * dv;
    acc += (o & 1) ? cos(arg) : sin(arg);
    h[((size_t)b*1024 + t)*512 + o] = acc;
  }
}

// ---------------- fp64 scalar GEMM 128x128x16, 8x8 microtile ----------------
// Per-output arithmetic BIT-IDENTICAL to the R6 64x64 kernel (same ascending-k
// FMA chain, same epilogue order) — only thread<->output assignment differs.
// B stays f32 in LDS (exact conversion on read): ratio 64 FMA / 96 LDS-bytes
// -> FMA-bound (78.6 TF ceiling) instead of LDS-BW-bound (39 TF).
// flags: 1=+bias, 2=gelu(exact), 4=qkv layout, 8=dup f32 store (qkv only), 16=accumulate into C
__global__ __launch_bounds__(256)
void dgemm_kernel(const double* __restrict__ A, const float* __restrict__ Bm,
                  const float* __restrict__ bias, double* __restrict__ C,
                  float* __restrict__ C32, int N, int K, int ldb, int flags) {
  __shared__ double As[16][130];
  __shared__ float  Bs[16][132];
  int tid = threadIdx.x;
  int tx = tid & 15, ty = tid >> 4;
  int arow = blockIdx.x * 128;
  int bcol = blockIdx.y * 128;
  int am = tid >> 1, ak = (tid & 1) * 8;
  int bk = tid >> 4, bn = (tid & 15) * 8;
  const double* aptr = A + (size_t)(arow + am)*K + ak;
  const float*  bptr = Bm + (size_t)bk*ldb + bcol + bn;
  double acc[8][8];
  #pragma unroll
  for (int i=0;i<8;++i)
    #pragma unroll
    for (int j=0;j<8;++j) acc[i][j]=0.0;
  for (int k0 = 0; k0 < K; k0 += 16) {
    double2 av0 = *(const double2*)(aptr + 0);
    double2 av1 = *(const double2*)(aptr + 2);
    double2 av2 = *(const double2*)(aptr + 4);
    double2 av3 = *(const double2*)(aptr + 6);
    float4 bv0 = *(const float4*)(bptr);
    float4 bv1 = *(const float4*)(bptr + 4);
    As[ak+0][am] = av0.x; As[ak+1][am] = av0.y;
    As[ak+2][am] = av1.x; As[ak+3][am] = av1.y;
    As[ak+4][am] = av2.x; As[ak+5][am] = av2.y;
    As[ak+6][am] = av3.x; As[ak+7][am] = av3.y;
    *(float4*)&Bs[bk][bn]   = bv0;
    *(float4*)&Bs[bk][bn+4] = bv1;
    __syncthreads();
    #pragma unroll
    for (int kk=0;kk<16;++kk) {
      double a[8];
      *(double2*)&a[0] = *(const double2*)&As[kk][2*ty];
      *(double2*)&a[2] = *(const double2*)&As[kk][2*ty+32];
      *(double2*)&a[4] = *(const double2*)&As[kk][2*ty+64];
      *(double2*)&a[6] = *(const double2*)&As[kk][2*ty+96];
      float2 f0 = *(const float2*)&Bs[kk][2*tx];
      float2 f1 = *(const float2*)&Bs[kk][2*tx+32];
      float2 f2 = *(const float2*)&Bs[kk][2*tx+64];
      float2 f3 = *(const float2*)&Bs[kk][2*tx+96];
      double b[8];
      b[0]=(double)f0.x; b[1]=(double)f0.y; b[2]=(double)f1.x; b[3]=(double)f1.y;
      b[4]=(double)f2.x; b[5]=(double)f2.y; b[6]=(double)f3.x; b[7]=(double)f3.y;
      #pragma unroll
      for (int i=0;i<8;++i)
        #pragma unroll
        for (int j=0;j<8;++j) acc[i][j] += a[i]*b[j];
    }
    __syncthreads();
    aptr += 16;
    bptr += (size_t)16*ldb;
  }
  #pragma unroll
  for (int i=0;i<8;++i) {
    int row = arow + 2*ty + (i&1) + 32*(i>>1);
    #pragma unroll
    for (int j=0;j<8;++j) {
      int col = bcol + 2*tx + (j&1) + 32*(j>>1);
      double cv = acc[i][j];
      if (flags & 1) cv += (double)bias[col];
      if (flags & 2) cv = 0.5*cv*(1.0 + erf(cv*0.70710678118654752440));
      if (flags & 4) {
        int b_ = row >> 10, t = row & 1023;
        int hd = col >> 6, dd = col & 63;
        size_t idx = (((size_t)b_*8 + hd)*1024 + t)*64 + dd;
        C[idx] = cv;
        if (flags & 8) C32[idx] = (float)cv;
      } else {
        size_t idx = (size_t)row*N + col;
        if (flags & 16) cv += C[idx];
        C[idx] = cv;
      }
    }
  }
}

// ---------------- fp32 GEMM 128x128x16, 8x8 microtile (conflict-free remap) ----------------
// flags: 1=+bias, 2=gelu(exact), 4=qkv layout
__global__ __launch_bounds__(256)
void sgemm_kernel(const float* __restrict__ A, const float* __restrict__ Bm,
                  const float* __restrict__ bias, float* __restrict__ C,
                  int N, int K, int flags) {
  __shared__ float As[16][128];
  __shared__ float Bs[16][128];
  int tid = threadIdx.x;
  int tx = tid & 15, ty = tid >> 4;
  float acc[8][8];
  #pragma unroll
  for (int i=0;i<8;++i)
    #pragma unroll
    for (int j=0;j<8;++j) acc[i][j]=0.f;
  const int arow = blockIdx.x*128;
  const int bcol = blockIdx.y*128;
  for (int k0 = 0; k0 < K; k0 += 16) {
    #pragma unroll
    for (int q = 0; q < 2; ++q) {
      int f4 = tid*2 + q;
      int r = f4 >> 2, c4 = f4 & 3;
      float4 av = *(const float4*)(A + (size_t)(arow + r)*K + k0 + c4*4);
      As[c4*4+0][r]=av.x; As[c4*4+1][r]=av.y; As[c4*4+2][r]=av.z; As[c4*4+3][r]=av.w;
      int kk = f4 >> 5, cc = f4 & 31;
      *(float4*)&Bs[kk][cc*4] = *(const float4*)(Bm + (size_t)(k0+kk)*N + bcol + cc*4);
    }
    __syncthreads();
    #pragma unroll
    for (int kk=0;kk<16;++kk) {
      float a[8], bb[8];
      #pragma unroll
      for (int i=0;i<8;++i) a[i] = As[kk][ty + 16*i];
      #pragma unroll
      for (int j=0;j<8;++j) bb[j] = Bs[kk][tx + 16*j];
      #pragma unroll
      for (int i=0;i<8;++i)
        #pragma unroll
        for (int j=0;j<8;++j) acc[i][j] += a[i]*bb[j];
    }
    __syncthreads();
  }
  #pragma unroll
  for (int i=0;i<8;++i) {
    int row = arow + ty + 16*i;
    #pragma unroll
    for (int j=0;j<8;++j) {
      int col = bcol + tx + 16*j;
      float cv = acc[i][j];
      if (flags & 1) cv += bias[col];
      if (flags & 2) cv = 0.5f*cv*(1.0f + erff(cv*0.70710678118654752f));
      if (flags & 4) {
        int b = row >> 10, t = row & 1023;
        int hd = col >> 6, dd = col & 63;
        C[(((size_t)b*8 + hd)*1024 + t)*64 + dd] = cv;
      } else {
        C[(size_t)row*N + col] = cv;
      }
    }
  }
}

// ---------------- LSH bucket assignment + per-round counting sort (fp64) ----------------
__global__ __launch_bounds__(256)
void bucket_sort_kernel(const double* __restrict__ qk, const float* __restrict__ rot,
                        int* __restrict__ sticker) {
  int bh = blockIdx.x >> 2, r = blockIdx.x & 3;
  __shared__ double rots[64][17];
  __shared__ unsigned char bucket[1024];
  __shared__ int cnt[32];
  __shared__ int off[32];
  int tid = threadIdx.x;
  for (int idx = tid; idx < 1024; idx += 256) {
    int f = idx >> 4, i = idx & 15;
    rots[f][i] = (double)rot[(f*4 + r)*16 + i];
  }
  if (tid < 32) cnt[tid] = 0;
  __syncthreads();
  for (int t = tid; t < 1024; t += 256) {
    const double* q = qk + ((size_t)bh*1024 + t)*64;
    double rv[16];
    #pragma unroll
    for (int i=0;i<16;++i) rv[i]=0.0;
    for (int f=0; f<64; ++f) {
      double qf = q[f];
      #pragma unroll
      for (int i=0;i<16;++i) rv[i] += qf * rots[f][i];
    }
    int best = 0; double bv = rv[0];
    #pragma unroll
    for (int i=1;i<16;++i) if (rv[i] > bv) { bv=rv[i]; best=i; }
    #pragma unroll
    for (int i=0;i<16;++i) { double nv = -rv[i]; if (nv > bv) { bv=nv; best=16+i; } }
    bucket[t] = (unsigned char)best;
    atomicAdd(&cnt[best], 1);
  }
  __syncthreads();
  if (tid == 0) {
    int s = 0;
    for (int k=0;k<32;++k) { off[k]=s; s+=cnt[k]; }
  }
  __syncthreads();
  if (tid < 32) {
    int pos = off[tid];
    int* outp = sticker + (size_t)bh*NT_ + r*1024;
    for (int t=0;t<1024;++t)
      if (bucket[t] == (unsigned char)tid) outp[pos++] = t;
  }
}

// ---------------- chunked LSH attention fp64 ----------------
__global__ __launch_bounds__(256)
void lsh_attn_kernel(const double* __restrict__ qk, const double* __restrict__ v,
                     const int* __restrict__ sticker,
                     double* __restrict__ obuf, double* __restrict__ lse, int bh0) {
  int bh_l = blockIdx.x >> 7;
  int bh = bh0 + bh_l;
  int c  = blockIdx.x & 127;
  int cprev = (c + 127) & 127;
  __shared__ double kv[64][66];
  __shared__ double pp[32][66];
  __shared__ double rnorm[64];
  __shared__ int tk[64];
  int tid = threadIdx.x;
  if (tid < 64) {
    int chunk = (tid < 32) ? c : cprev;
    tk[tid] = sticker[(size_t)bh*NT_ + chunk*32 + (tid & 31)];
  }
  __syncthreads();
  for (int idx = tid; idx < 2048; idx += 256) {
    int j = idx >> 5, c2 = (idx & 31)*2;
    *(double2*)&kv[j][c2] = *(const double2*)(qk + ((size_t)bh*1024 + tk[j])*64 + c2);
  }
  __syncthreads();
  if (tid < 64) {
    double s = 0.0;
    #pragma unroll
    for (int f=0; f<64; ++f) { double x = kv[tid][f]; s += x*x; }
    rnorm[tid] = 1.0 / fmax(sqrt(s), 1e-12);
  }
  __syncthreads();
  int i = tid >> 3, sub = tid & 7;
  int ti = tk[i];
  double dots[8];
  double dmax = -1.0e300;
  #pragma unroll
  for (int jj=0; jj<8; ++jj) {
    int j = sub*8 + jj;
    double s = 0.0;
    #pragma unroll
    for (int f=0; f<64; ++f) s += kv[i][f] * kv[j][f];
    s *= rnorm[j] * 0.125;
    if (ti == tk[j]) s = MASKSELF64;
    dots[jj] = s;
    dmax = fmax(dmax, s);
  }
  #pragma unroll
  for (int w=1; w<8; w<<=1) dmax = fmax(dmax, __shfl_xor(dmax, w, 64));
  double esum = 0.0;
  #pragma unroll
  for (int jj=0; jj<8; ++jj) {
    double e = exp(dots[jj] - dmax);
    esum += e;
    pp[i][sub*8+jj] = e;
  }
  #pragma unroll
  for (int w=1; w<8; w<<=1) esum += __shfl_xor(esum, w, 64);
  __syncthreads();
  for (int idx = tid; idx < 2048; idx += 256) {
    int j = idx >> 5, c2 = (idx & 31)*2;
    *(double2*)&kv[j][c2] = *(const double2*)(v + ((size_t)bh*1024 + tk[j])*64 + c2);
  }
  __syncthreads();
  double ov[8];
  #pragma unroll
  for (int dd=0;dd<8;++dd) ov[dd]=0.0;
  for (int j=0;j<64;++j) {
    double p = pp[i][j];
    #pragma unroll
    for (int dd=0;dd<8;++dd) ov[dd] += p * kv[j][sub*8+dd];
  }
  double rinv = 1.0 / esum;
  int r = c >> 5;
  size_t ob = (((size_t)bh_l*4 + r)*1024 + ti)*64 + sub*8;
  #pragma unroll
  for (int dd=0;dd<8;++dd) obuf[ob + dd] = ov[dd]*rinv;
  if (sub == 0) lse[((size_t)bh*4 + r)*1024 + ti] = log(esum) + dmax;
}

// ---------------- combine rounds (fp64) ----------------
__global__ __launch_bounds__(256)
void combine_kernel(const double* __restrict__ obuf, const double* __restrict__ lse,
                    double* __restrict__ comb, int bh0) {
  int g = blockIdx.x*4 + (threadIdx.x >> 6);
  int bh_l = g >> 10, t = g & 1023;
  int bh = bh0 + bh_l;
  int d = threadIdx.x & 63;
  double l[4];
  #pragma unroll
  for (int r=0;r<4;++r) l[r] = lse[((size_t)bh*4 + r)*1024 + t];
  double m = fmax(fmax(l[0],l[1]), fmax(l[2],l[3]));
  double e[4], s=0.0;
  #pragma unroll
  for (int r=0;r<4;++r){ e[r]=exp(l[r]-m); s+=e[r]; }
  double rs = 1.0/s;
  double o = 0.0;
  #pragma unroll
  for (int r=0;r<4;++r)
    o += e[r]*rs * obuf[(((size_t)bh_l*4 + r)*1024 + t)*64 + d];
  int b = bh >> 3, hd = bh & 7;
  comb[((size_t)b*1024 + t)*512 + hd*64 + d] = o;
}

// ---------------- chunked LSH attention fp32 (layer-2 value path) ----------------
__global__ __launch_bounds__(256)
void lsh_attn32_kernel(const float* __restrict__ qk, const float* __restrict__ v,
                       const int* __restrict__ sticker,
                       float* __restrict__ obuf, float* __restrict__ lse, int bh0) {
  int bh_l = blockIdx.x >> 7;
  int bh = bh0 + bh_l;
  int c  = blockIdx.x & 127;
  int cprev = (c + 127) & 127;
  __shared__ float kv[64][68];
  __shared__ float pp[32][68];
  __shared__ float rnorm[64];
  __shared__ int tk[64];
  int tid = threadIdx.x;
  if (tid < 64) {
    int chunk = (tid < 32) ? c : cprev;
    tk[tid] = sticker[(size_t)bh*NT_ + chunk*32 + (tid & 31)];
  }
  __syncthreads();
  for (int idx = tid; idx < 1024; idx += 256) {
    int j = idx >> 4, c4 = (idx & 15)*4;
    *(float4*)&kv[j][c4] = *(const float4*)(qk + ((size_t)bh*1024 + tk[j])*64 + c4);
  }
  __syncthreads();
  if (tid < 64) {
    float s = 0.f;
    #pragma unroll
    for (int f=0; f<64; ++f) { float x = kv[tid][f]; s += x*x; }
    rnorm[tid] = 1.0f / fmaxf(sqrtf(s), 1e-12f);
  }
  __syncthreads();
  int i = tid >> 3, sub = tid & 7;
  int ti = tk[i];
  float dots[8];
  float dmax = -1.0e30f;
  #pragma unroll
  for (int jj=0; jj<8; ++jj) {
    int j = sub*8 + jj;
    float s = 0.f;
    #pragma unroll
    for (int f=0; f<64; ++f) s += kv[i][f] * kv[j][f];
    s *= rnorm[j] * 0.125f;
    if (ti == tk[j]) s = MASKSELF32;
    dots[jj] = s;
    dmax = fmaxf(dmax, s);
  }
  #pragma unroll
  for (int w=1; w<8; w<<=1) dmax = fmaxf(dmax, __shfl_xor(dmax, w, 64));
  float esum = 0.f;
  #pragma unroll
  for (int jj=0; jj<8; ++jj) {
    float e = expf(dots[jj] - dmax);
    esum += e;
    pp[i][sub*8+jj] = e;
  }
  #pragma unroll
  for (int w=1; w<8; w<<=1) esum += __shfl_xor(esum, w, 64);
  __syncthreads();
  for (int idx = tid; idx < 1024; idx += 256) {
    int j = idx >> 4, c4 = (idx & 15)*4;
    *(float4*)&kv[j][c4] = *(const float4*)(v + ((size_t)bh*1024 + tk[j])*64 + c4);
  }
  __syncthreads();
  float ov[8];
  #pragma unroll
  for (int dd=0;dd<8;++dd) ov[dd]=0.f;
  for (int j=0;j<64;++j) {
    float p = pp[i][j];
    #pragma unroll
    for (int dd=0;dd<8;++dd) ov[dd] += p * kv[j][sub*8+dd];
  }
  float rinv = 1.0f / esum;
  int r = c >> 5;
  size_t ob = (((size_t)bh_l*4 + r)*1024 + ti)*64 + sub*8;
  #pragma unroll
  for (int dd=0;dd<8;++dd) obuf[ob + dd] = ov[dd]*rinv;
  if (sub == 0) lse[((size_t)bh*4 + r)*1024 + ti] = logf(esum) + dmax;
}

// ---------------- combine rounds (fp32) ----------------
__global__ __launch_bounds__(256)
void combine32_kernel(const float* __restrict__ obuf, const float* __restrict__ lse,
                      float* __restrict__ comb, int bh0) {
  int g = blockIdx.x*4 + (threadIdx.x >> 6);
  int bh_l = g >> 10, t = g & 1023;
  int bh = bh0 + bh_l;
  int d = threadIdx.x & 63;
  float l[4];
  #pragma unroll
  for (int r=0;r<4;++r) l[r] = lse[((size_t)bh*4 + r)*1024 + t];
  float m = fmaxf(fmaxf(l[0],l[1]), fmaxf(l[2],l[3]));
  float e[4], s=0.f;
  #pragma unroll
  for (int r=0;r<4;++r){ e[r]=expf(l[r]-m); s+=e[r]; }
  float rs = 1.0f/s;
  float o = 0.f;
  #pragma unroll
  for (int r=0;r<4;++r)
    o += e[r]*rs * obuf[(((size_t)bh_l*4 + r)*1024 + t)*64 + d];
  int b = bh >> 3, hd = bh & 7;
  comb[((size_t)b*1024 + t)*512 + hd*64 + d] = o;
}

// ---------------- layernorm fp64 (optional residual, optional f32 dup) ----------------
__global__ __launch_bounds__(256)
void ln_kernel(const double* __restrict__ x, const double* __restrict__ res,
               const float* __restrict__ gw, const float* __restrict__ bw,
               double* __restrict__ outp, float* __restrict__ out32) {
  int row = blockIdx.x;
  int tid = threadIdx.x;
  const double* xr = x + (size_t)row*512;
  double v0 = xr[tid], v1 = xr[tid+256];
  if (res) { const double* rr = res + (size_t)row*512; v0 += rr[tid]; v1 += rr[tid+256]; }
  double s = v0 + v1;
  #pragma unroll
  for (int w=1; w<64; w<<=1) s += __shfl_xor(s, w, 64);
  __shared__ double red[4];
  int wid = tid >> 6, lane = tid & 63;
  if (lane == 0) red[wid] = s;
  __syncthreads();
  s = red[0]+red[1]+red[2]+red[3];
  double m = s * (1.0/512.0);
  double d0 = v0 - m, d1 = v1 - m;
  double q = d0*d0 + d1*d1;
  #pragma unroll
  for (int w=1; w<64; w<<=1) q += __shfl_xor(q, w, 64);
  __syncthreads();
  if (lane == 0) red[wid] = q;
  __syncthreads();
  q = red[0]+red[1]+red[2]+red[3];
  double var = q * (1.0/512.0);
  double rstd = 1.0 / sqrt(var + 1e-5);
  double o0 = d0*rstd*(double)gw[tid] + (double)bw[tid];
  double o1 = d1*rstd*(double)gw[tid+256] + (double)bw[tid+256];
  outp[(size_t)row*512 + tid]       = o0;
  outp[(size_t)row*512 + tid + 256] = o1;
  if (out32) {
    out32[(size_t)row*512 + tid]       = (float)o0;
    out32[(size_t)row*512 + tid + 256] = (float)o1;
  }
}

// ---------------- layernorm: x f64 + res f32 -> f32 ----------------
__global__ __launch_bounds__(256)
void lnmx_kernel(const double* __restrict__ x, const float* __restrict__ res,
                 const float* __restrict__ gw, const float* __restrict__ bw,
                 float* __restrict__ out32) {
  int row = blockIdx.x;
  int tid = threadIdx.x;
  const double* xr = x + (size_t)row*512;
  const float*  rr = res + (size_t)row*512;
  double v0 = xr[tid] + (double)rr[tid];
  double v1 = xr[tid+256] + (double)rr[tid+256];
  double s = v0 + v1;
  #pragma unroll
  for (int w=1; w<64; w<<=1) s += __shfl_xor(s, w, 64);
  __shared__ double red[4];
  int wid = tid >> 6, lane = tid & 63;
  if (lane == 0) red[wid] = s;
  __syncthreads();
  s = red[0]+red[1]+red[2]+red[3];
  double m = s * (1.0/512.0);
  double d0 = v0 - m, d1 = v1 - m;
  double q = d0*d0 + d1*d1;
  #pragma unroll
  for (int w=1; w<64; w<<=1) q += __shfl_xor(q, w, 64);
  __syncthreads();
  if (lane == 0) red[wid] = q;
  __syncthreads();
  q = red[0]+red[1]+red[2]+red[3];
  double rstd = 1.0 / sqrt(q * (1.0/512.0) + 1e-5);
  out32[(size_t)row*512 + tid]       = (float)(d0*rstd*(double)gw[tid] + (double)bw[tid]);
  out32[(size_t)row*512 + tid + 256] = (float)(d1*rstd*(double)gw[tid+256] + (double)bw[tid+256]);
}

// ---------------- layernorm f32 in/out (double stats), optional residual ----------------
__global__ __launch_bounds__(256)
void ln32_kernel(const float* __restrict__ x, const float* __restrict__ res,
                 const float* __restrict__ gw, const float* __restrict__ bw,
                 float* __restrict__ out32) {
  int row = blockIdx.x;
  int tid = threadIdx.x;
  const float* xr = x + (size_t)row*512;
  double v0 = (double)xr[tid], v1 = (double)xr[tid+256];
  if (res) { const float* rr = res + (size_t)row*512; v0 += (double)rr[tid]; v1 += (double)rr[tid+256]; }
  double s = v0 + v1;
  #pragma unroll
  for (int w=1; w<64; w<<=1) s += __shfl_xor(s, w, 64);
  __shared__ double red[4];
  int wid = tid >> 6, lane = tid & 63;
  if (lane == 0) red[wid] = s;
  __syncthreads();
  s = red[0]+red[1]+red[2]+red[3];
  double m = s * (1.0/512.0);
  double d0 = v0 - m, d1 = v1 - m;
  double q = d0*d0 + d1*d1;
  #pragma unroll
  for (int w=1; w<64; w<<=1) q += __shfl_xor(q, w, 64);
  __syncthreads();
  if (lane == 0) red[wid] = q;
  __syncthreads();
  q = red[0]+red[1]+red[2]+red[3];
  double rstd = 1.0 / sqrt(q * (1.0/512.0) + 1e-5);
  out32[(size_t)row*512 + tid]       = (float)(d0*rstd*(double)gw[tid] + (double)bw[tid]);
  out32[(size_t)row*512 + tid + 256] = (float)(d1*rstd*(double)gw[tid+256] + (double)bw[tid+256]);
}

// ---------------- final projection (f32 input, f64 accum, f32 store) ----------------
__global__ __launch_bounds__(64)
void proj_kernel(const float* __restrict__ hf, const float* __restrict__ pw,
                 const float* __restrict__ pb, float* __restrict__ outp) {
  int row = blockIdx.x;
  int b = row >> 8, tp = row & 255;
  const float* hr = hf + ((size_t)b*1024 + 768 + tp)*512;
  int lane = threadIdx.x;
  double acc[7];
  #pragma unroll
  for (int cc=0;cc<7;++cc) acc[cc]=0.0;
  for (int d = lane; d < 512; d += 64) {
    double hv = (double)hr[d];
    #pragma unroll
    for (int cc=0;cc<7;++cc) acc[cc] += hv * (double)pw[d*7 + cc];
  }
  #pragma unroll
  for (int cc=0;cc<7;++cc) {
    double s = acc[cc];
    #pragma unroll
    for (int w=32;w>=1;w>>=1) s += __shfl_xor(s, w, 64);
    if (lane == 0) outp[(size_t)row*7 + cc] = (float)(s + (double)pb[cc]);
  }
}

extern "C" void kernel_launch(void* const* d_in, const int* in_sizes, int n_in,
                              void* d_out, int out_size, void* d_ws, size_t ws_size,
                              hipStream_t stream) {
  (void)in_sizes; (void)n_in; (void)out_size; (void)ws_size;
  const float* x_enc      = (const float*)d_in[0];
  const float* x_mark_enc = (const float*)d_in[1];
  const float* x_dec      = (const float*)d_in[2];
  const float* x_mark_dec = (const float*)d_in[3];
  const float* conv_w     = (const float*)d_in[4];
  const float* mark_w     = (const float*)d_in[5];
  const float* qk_w       = (const float*)d_in[6];
  const float* v_w        = (const float*)d_in[7];
  const float* out_w      = (const float*)d_in[8];
  const float* out_b      = (const float*)d_in[9];
  const float* ln1_g      = (const float*)d_in[10];
  const float* ln1_b      = (const float*)d_in[11];
  const float* ln2_g      = (const float*)d_in[12];
  const float* ln2_b      = (const float*)d_in[13];
  const float* ffn_w1     = (const float*)d_in[14];
  const float* ffn_b1     = (const float*)d_in[15];
  const float* ffn_w2     = (const float*)d_in[16];
  const float* ffn_b2     = (const float*)d_in[17];
  const float* lnf_g      = (const float*)d_in[18];
  const float* lnf_b      = (const float*)d_in[19];
  const float* proj_w     = (const float*)d_in[20];
  const float* proj_b     = (const float*)d_in[21];
  const float* rotations  = (const float*)d_in[22];

  char* ws = (char*)d_ws;
  // regions: A [0,64M) B [64,128M) C [128,192M) D [192,224M)
  double* h64   = (double*)(ws);               // A
  double* qk64  = (double*)(ws + 67108864);    // B: qk64 / ffn1 hidden slice
  double* v64   = (double*)(ws + 134217728);   // C: v64 / comb / ffn2 accumulator
  double* obuf  = (double*)(ws + 201326592);   // D: o_rounds (16 bh)
  int*    stick = (int*)   (ws + 234881024);   // [224,226M)
  double* lse64 = (double*)(ws + 236978176);   // [226,230M)
  float*  lse32 = (float*) (ws + 236978176);
  double* comb  = v64;
  // layer-2 f32 aliases
  float* h32    = (float*)(ws + 201326592);    // D    (obuf dead after layer-1 attn)
  float* qk32   = (float*)(ws + 134217728);    // C0 [128,160)
  float* v32    = (float*)(ws + 167772160);    // C1 [160,192)
  float* obuf32 = (float*)(ws + 67108864);     // B0 [64,96)   (qk64 dead after bucket_sort)
  float* comb32 = (float*)(ws + 100663296);    // B1 [96,128)
  float* ao32   = (float*)(ws + 201326592);    // D   (h32 dead after v-GEMM)
  float* hA32   = (float*)(ws + 134217728);    // C0  (qk32 dead after attn)
  float* hid32  = (float*)(ws);                // A+B [0,128M) full f32 hidden
  float* y32    = (float*)(ws + 167772160);    // C1  (v32 dead)
  float* h2f    = (float*)(ws + 201326592);    // D   (ao32 dead)
  float* hf32   = (float*)(ws);                // A0 [0,32M) (hid32 dead)

  embed_kernel<<<16384, 256, 0, stream>>>(x_enc, x_mark_enc, x_dec, x_mark_dec,
                                          conv_w, mark_w, h64);

  // ================= layer 0 : full fp64 =================
  dgemm_kernel<<<dim3(128,4), 256, 0, stream>>>(h64, qk_w, nullptr, qk64, nullptr,
                                                512, 512, 512, 4);
  dgemm_kernel<<<dim3(128,4), 256, 0, stream>>>(h64, v_w, nullptr, v64, nullptr,
                                                512, 512, 512, 4);
  bucket_sort_kernel<<<512, 256, 0, stream>>>(qk64, rotations, stick);
  for (int g = 0; g < 8; ++g) {
    lsh_attn_kernel<<<2048, 256, 0, stream>>>(qk64, v64, stick, obuf, lse64, g*16);
    combine_kernel<<<4096, 256, 0, stream>>>(obuf, lse64, comb, g*16);
  }
  dgemm_kernel<<<dim3(128,4), 256, 0, stream>>>(comb, out_w, out_b, qk64, nullptr,
                                                512, 512, 512, 1);
  ln_kernel<<<16384, 256, 0, stream>>>(h64, qk64, ln1_g, ln1_b, h64, nullptr);
  for (int c = 0; c < 4; ++c) {   // FFN col-chunked: hidden slice [16384][512] f64 in qk64
    dgemm_kernel<<<dim3(128,4), 256, 0, stream>>>(h64, ffn_w1 + c*512,
                                                  ffn_b1 + c*512, qk64, nullptr,
                                                  512, 512, 2048, 3);
    dgemm_kernel<<<dim3(128,4), 256, 0, stream>>>(qk64, ffn_w2 + (size_t)c*512*512,
                                                  ffn_b2, comb, nullptr,
                                                  512, 512, 512, (c == 0) ? 1 : 16);
  }
  ln_kernel<<<16384, 256, 0, stream>>>(h64, comb, ln2_g, ln2_b, h64, h32);

  // ================= layer 1 : f64 decisions, f32 values =================
  sgemm_kernel<<<dim3(128,4), 256, 0, stream>>>(h32, v_w + 262144, nullptr, v32,
                                                512, 512, 4);
  dgemm_kernel<<<dim3(128,4), 256, 0, stream>>>(h64, qk_w + 262144, nullptr, qk64, qk32,
                                                512, 512, 512, 4 | 8);
  bucket_sort_kernel<<<512, 256, 0, stream>>>(qk64, rotations + 4096, stick);
  for (int g = 0; g < 4; ++g) {
    lsh_attn32_kernel<<<4096, 256, 0, stream>>>(qk32, v32, stick, obuf32, lse32, g*32);
    combine32_kernel<<<8192, 256, 0, stream>>>(obuf32, lse32, comb32, g*32);
  }
  sgemm_kernel<<<dim3(128,4), 256, 0, stream>>>(comb32, out_w + 262144, out_b + 512,
                                                ao32, 512, 512, 1);
  lnmx_kernel<<<16384, 256, 0, stream>>>(h64, ao32, ln1_g + 512, ln1_b + 512, hA32);
  sgemm_kernel<<<dim3(128,16), 256, 0, stream>>>(hA32, ffn_w1 + 1048576, ffn_b1 + 2048,
                                                 hid32, 2048, 512, 3);
  sgemm_kernel<<<dim3(128,4), 256, 0, stream>>>(hid32, ffn_w2 + 1048576, ffn_b2 + 512,
                                                y32, 512, 2048, 1);
  ln32_kernel<<<16384, 256, 0, stream>>>(hA32, y32, ln2_g + 512, ln2_b + 512, h2f);
  ln32_kernel<<<16384, 256, 0, stream>>>(h2f, nullptr, lnf_g, lnf_b, hf32);
  proj_kernel<<<4096, 64, 0, stream>>>(hf32, proj_w, proj_b, (float*)d_out);
}

// Round 8
// 5487.167 us; speedup vs baseline: 1.8222x; 1.0448x over previous
//
#include <hip/hip_runtime.h>
#include <math.h>

#define T_ 1024
#define NT_ 4096
#define MASKSELF64 -50000.0
#define MASKSELF32 -50000.0f

// ---------------- embedding (fp64) ----------------
__global__ __launch_bounds__(256)
void embed_kernel(const float* __restrict__ x_enc, const float* __restrict__ x_mark_enc,
                  const float* __restrict__ x_dec, const float* __restrict__ x_mark_dec,
                  const float* __restrict__ conv_w, const float* __restrict__ mark_w,
                  double* __restrict__ h) {
  int bt = blockIdx.x;
  int b = bt >> 10, t = bt & 1023;
  __shared__ double xs[3][7];
  __shared__ double xm[4];
  int tid = threadIdx.x;
  if (tid < 21) {
    int k = tid / 7, i = tid % 7;
    int tt = t + k - 1;
    if (tt < 0) tt += 1024;
    if (tt >= 1024) tt -= 1024;
    xs[k][i] = (double)((tt < 768) ? x_enc[((size_t)b*768 + tt)*7 + i]
                                   : x_dec[((size_t)b*512 + (tt - 512))*7 + i]);
  }
  if (tid >= 32 && tid < 36) {
    int m = tid - 32;
    xm[m] = (double)((t < 768) ? x_mark_enc[((size_t)b*768 + t)*4 + m]
                               : x_mark_dec[((size_t)b*512 + (t - 512))*4 + m]);
  }
  __syncthreads();
  for (int o = tid; o < 512; o += 256) {
    double acc = 0.0;
    #pragma unroll
    for (int k = 0; k < 3; ++k)
      #pragma unroll
      for (int i = 0; i < 7; ++i)
        acc += xs[k][i] * (double)conv_w[(o*7 + i)*3 + k];
    #pragma unroll
    for (int m = 0; m < 4; ++m) acc += xm[m] * (double)mark_w[m*512 + o];
    int j2 = o & ~1;
    double dv = exp((double)j2 * (-9.210340371976184 / 512.0));
    double arg = (double)t * dv;
    acc += (o & 1) ? cos(arg) : sin(arg);
    h[((size_t)b*1024 + t)*512 + o] = acc;
  }
}

// ---------------- fp64 scalar GEMM 128x128x16, 8x8 microtile, reg double-buffer ----------------
// Per-output arithmetic BIT-IDENTICAL to R6/R7 (same ascending-k FMA chain, same
// epilogue order) — prefetch changes only load scheduling.
// flags: 1=+bias, 2=gelu(exact), 4=qkv layout, 8=dup f32 store (qkv only), 16=accumulate into C
__global__ __launch_bounds__(256)
void dgemm_kernel(const double* __restrict__ A, const float* __restrict__ Bm,
                  const float* __restrict__ bias, double* __restrict__ C,
                  float* __restrict__ C32, int N, int K, int ldb, int flags) {
  __shared__ double As[16][130];
  __shared__ float  Bs[16][132];
  int tid = threadIdx.x;
  int tx = tid & 15, ty = tid >> 4;
  int arow = blockIdx.x * 128;
  int bcol = blockIdx.y * 128;
  int am = tid >> 1, ak = (tid & 1) * 8;
  int bk = tid >> 4, bn = (tid & 15) * 8;
  const double* aptr = A + (size_t)(arow + am)*K + ak;
  const float*  bptr = Bm + (size_t)bk*ldb + bcol + bn;
  double acc[8][8];
  #pragma unroll
  for (int i=0;i<8;++i)
    #pragma unroll
    for (int j=0;j<8;++j) acc[i][j]=0.0;
  double2 av0 = *(const double2*)(aptr + 0);
  double2 av1 = *(const double2*)(aptr + 2);
  double2 av2 = *(const double2*)(aptr + 4);
  double2 av3 = *(const double2*)(aptr + 6);
  float4 bv0 = *(const float4*)(bptr);
  float4 bv1 = *(const float4*)(bptr + 4);
  for (int k0 = 0; k0 < K; k0 += 16) {
    As[ak+0][am] = av0.x; As[ak+1][am] = av0.y;
    As[ak+2][am] = av1.x; As[ak+3][am] = av1.y;
    As[ak+4][am] = av2.x; As[ak+5][am] = av2.y;
    As[ak+6][am] = av3.x; As[ak+7][am] = av3.y;
    *(float4*)&Bs[bk][bn]   = bv0;
    *(float4*)&Bs[bk][bn+4] = bv1;
    __syncthreads();
    if (k0 + 16 < K) {                 // prefetch next tile while computing this one
      aptr += 16;
      bptr += (size_t)16*ldb;
      av0 = *(const double2*)(aptr + 0);
      av1 = *(const double2*)(aptr + 2);
      av2 = *(const double2*)(aptr + 4);
      av3 = *(const double2*)(aptr + 6);
      bv0 = *(const float4*)(bptr);
      bv1 = *(const float4*)(bptr + 4);
    }
    #pragma unroll
    for (int kk=0;kk<16;++kk) {
      double a[8];
      *(double2*)&a[0] = *(const double2*)&As[kk][2*ty];
      *(double2*)&a[2] = *(const double2*)&As[kk][2*ty+32];
      *(double2*)&a[4] = *(const double2*)&As[kk][2*ty+64];
      *(double2*)&a[6] = *(const double2*)&As[kk][2*ty+96];
      float2 f0 = *(const float2*)&Bs[kk][2*tx];
      float2 f1 = *(const float2*)&Bs[kk][2*tx+32];
      float2 f2 = *(const float2*)&Bs[kk][2*tx+64];
      float2 f3 = *(const float2*)&Bs[kk][2*tx+96];
      double b[8];
      b[0]=(double)f0.x; b[1]=(double)f0.y; b[2]=(double)f1.x; b[3]=(double)f1.y;
      b[4]=(double)f2.x; b[5]=(double)f2.y; b[6]=(double)f3.x; b[7]=(double)f3.y;
      #pragma unroll
      for (int i=0;i<8;++i)
        #pragma unroll
        for (int j=0;j<8;++j) acc[i][j] += a[i]*b[j];
    }
    __syncthreads();
  }
  #pragma unroll
  for (int i=0;i<8;++i) {
    int row = arow + 2*ty + (i&1) + 32*(i>>1);
    #pragma unroll
    for (int j=0;j<8;++j) {
      int col = bcol + 2*tx + (j&1) + 32*(j>>1);
      double cv = acc[i][j];
      if (flags & 1) cv += (double)bias[col];
      if (flags & 2) cv = 0.5*cv*(1.0 + erf(cv*0.70710678118654752440));
      if (flags & 4) {
        int b_ = row >> 10, t = row & 1023;
        int hd = col >> 6, dd = col & 63;
        size_t idx = (((size_t)b_*8 + hd)*1024 + t)*64 + dd;
        C[idx] = cv;
        if (flags & 8) C32[idx] = (float)cv;
      } else {
        size_t idx = (size_t)row*N + col;
        if (flags & 16) cv += C[idx];
        C[idx] = cv;
      }
    }
  }
}

// ---------------- fp32 GEMM 128x128x16, 8x8 microtile, reg double-buffer ----------------
// flags: 1=+bias, 2=gelu(exact), 4=qkv layout
__global__ __launch_bounds__(256)
void sgemm_kernel(const float* __restrict__ A, const float* __restrict__ Bm,
                  const float* __restrict__ bias, float* __restrict__ C,
                  int N, int K, int flags) {
  __shared__ float As[16][128];
  __shared__ float Bs[16][128];
  int tid = threadIdx.x;
  int tx = tid & 15, ty = tid >> 4;
  float acc[8][8];
  #pragma unroll
  for (int i=0;i<8;++i)
    #pragma unroll
    for (int j=0;j<8;++j) acc[i][j]=0.f;
  const int arow = blockIdx.x*128;
  const int bcol = blockIdx.y*128;
  int e0 = tid*2, e1 = tid*2 + 1;
  int ra0 = e0 >> 2, ca0 = (e0 & 3)*4;
  int ra1 = e1 >> 2, ca1 = (e1 & 3)*4;
  int kb0 = e0 >> 5, cb0 = (e0 & 31)*4;
  int kb1 = e1 >> 5, cb1 = (e1 & 31)*4;
  const float* pA0 = A + (size_t)(arow + ra0)*K + ca0;
  const float* pA1 = A + (size_t)(arow + ra1)*K + ca1;
  const float* pB0 = Bm + (size_t)kb0*N + bcol + cb0;
  const float* pB1 = Bm + (size_t)kb1*N + bcol + cb1;
  float4 va0 = *(const float4*)pA0;
  float4 va1 = *(const float4*)pA1;
  float4 vb0 = *(const float4*)pB0;
  float4 vb1 = *(const float4*)pB1;
  for (int k0 = 0; k0 < K; k0 += 16) {
    As[ca0+0][ra0]=va0.x; As[ca0+1][ra0]=va0.y; As[ca0+2][ra0]=va0.z; As[ca0+3][ra0]=va0.w;
    As[ca1+0][ra1]=va1.x; As[ca1+1][ra1]=va1.y; As[ca1+2][ra1]=va1.z; As[ca1+3][ra1]=va1.w;
    *(float4*)&Bs[kb0][cb0] = vb0;
    *(float4*)&Bs[kb1][cb1] = vb1;
    __syncthreads();
    if (k0 + 16 < K) {                 // prefetch next tile
      pA0 += 16; pA1 += 16;
      pB0 += (size_t)16*N; pB1 += (size_t)16*N;
      va0 = *(const float4*)pA0;
      va1 = *(const float4*)pA1;
      vb0 = *(const float4*)pB0;
      vb1 = *(const float4*)pB1;
    }
    #pragma unroll
    for (int kk=0;kk<16;++kk) {
      float a[8], bb[8];
      #pragma unroll
      for (int i=0;i<8;++i) a[i] = As[kk][ty + 16*i];
      #pragma unroll
      for (int j=0;j<8;++j) bb[j] = Bs[kk][tx + 16*j];
      #pragma unroll
      for (int i=0;i<8;++i)
        #pragma unroll
        for (int j=0;j<8;++j) acc[i][j] += a[i]*bb[j];
    }
    __syncthreads();
  }
  #pragma unroll
  for (int i=0;i<8;++i) {
    int row = arow + ty + 16*i;
    #pragma unroll
    for (int j=0;j<8;++j) {
      int col = bcol + tx + 16*j;
      float cv = acc[i][j];
      if (flags & 1) cv += bias[col];
      if (flags & 2) cv = 0.5f*cv*(1.0f + erff(cv*0.70710678118654752f));
      if (flags & 4) {
        int b = row >> 10, t = row & 1023;
        int hd = col >> 6, dd = col & 63;
        C[(((size_t)b*8 + hd)*1024 + t)*64 + dd] = cv;
      } else {
        C[(size_t)row*N + col] = cv;
      }
    }
  }
}

// ---------------- LSH bucket assignment + per-round counting sort (fp64) ----------------
__global__ __launch_bounds__(256)
void bucket_sort_kernel(const double* __restrict__ qk, const float* __restrict__ rot,
                        int* __restrict__ sticker) {
  int bh = blockIdx.x >> 2, r = blockIdx.x & 3;
  __shared__ double rots[64][17];
  __shared__ unsigned char bucket[1024];
  __shared__ int cnt[32];
  __shared__ int off[32];
  int tid = threadIdx.x;
  for (int idx = tid; idx < 1024; idx += 256) {
    int f = idx >> 4, i = idx & 15;
    rots[f][i] = (double)rot[(f*4 + r)*16 + i];
  }
  if (tid < 32) cnt[tid] = 0;
  __syncthreads();
  for (int t = tid; t < 1024; t += 256) {
    const double* q = qk + ((size_t)bh*1024 + t)*64;
    double rv[16];
    #pragma unroll
    for (int i=0;i<16;++i) rv[i]=0.0;
    for (int f=0; f<64; ++f) {
      double qf = q[f];
      #pragma unroll
      for (int i=0;i<16;++i) rv[i] += qf * rots[f][i];
    }
    int best = 0; double bv = rv[0];
    #pragma unroll
    for (int i=1;i<16;++i) if (rv[i] > bv) { bv=rv[i]; best=i; }
    #pragma unroll
    for (int i=0;i<16;++i) { double nv = -rv[i]; if (nv > bv) { bv=nv; best=16+i; } }
    bucket[t] = (unsigned char)best;
    atomicAdd(&cnt[best], 1);
  }
  __syncthreads();
  if (tid == 0) {
    int s = 0;
    for (int k=0;k<32;++k) { off[k]=s; s+=cnt[k]; }
  }
  __syncthreads();
  if (tid < 32) {
    int pos = off[tid];
    int* outp = sticker + (size_t)bh*NT_ + r*1024;
    for (int t=0;t<1024;++t)
      if (bucket[t] == (unsigned char)tid) outp[pos++] = t;
  }
}

// ---------------- chunked LSH attention fp64 ----------------
__global__ __launch_bounds__(256)
void lsh_attn_kernel(const double* __restrict__ qk, const double* __restrict__ v,
                     const int* __restrict__ sticker,
                     double* __restrict__ obuf, double* __restrict__ lse, int bh0) {
  int bh_l = blockIdx.x >> 7;
  int bh = bh0 + bh_l;
  int c  = blockIdx.x & 127;
  int cprev = (c + 127) & 127;
  __shared__ double kv[64][66];
  __shared__ double pp[32][66];
  __shared__ double rnorm[64];
  __shared__ int tk[64];
  int tid = threadIdx.x;
  if (tid < 64) {
    int chunk = (tid < 32) ? c : cprev;
    tk[tid] = sticker[(size_t)bh*NT_ + chunk*32 + (tid & 31)];
  }
  __syncthreads();
  for (int idx = tid; idx < 2048; idx += 256) {
    int j = idx >> 5, c2 = (idx & 31)*2;
    *(double2*)&kv[j][c2] = *(const double2*)(qk + ((size_t)bh*1024 + tk[j])*64 + c2);
  }
  __syncthreads();
  if (tid < 64) {
    double s = 0.0;
    #pragma unroll
    for (int f=0; f<64; ++f) { double x = kv[tid][f]; s += x*x; }
    rnorm[tid] = 1.0 / fmax(sqrt(s), 1e-12);
  }
  __syncthreads();
  int i = tid >> 3, sub = tid & 7;
  int ti = tk[i];
  double dots[8];
  double dmax = -1.0e300;
  #pragma unroll
  for (int jj=0; jj<8; ++jj) {
    int j = sub*8 + jj;
    double s = 0.0;
    #pragma unroll
    for (int f=0; f<64; ++f) s += kv[i][f] * kv[j][f];
    s *= rnorm[j] * 0.125;
    if (ti == tk[j]) s = MASKSELF64;
    dots[jj] = s;
    dmax = fmax(dmax, s);
  }
  #pragma unroll
  for (int w=1; w<8; w<<=1) dmax = fmax(dmax, __shfl_xor(dmax, w, 64));
  double esum = 0.0;
  #pragma unroll
  for (int jj=0; jj<8; ++jj) {
    double e = exp(dots[jj] - dmax);
    esum += e;
    pp[i][sub*8+jj] = e;
  }
  #pragma unroll
  for (int w=1; w<8; w<<=1) esum += __shfl_xor(esum, w, 64);
  __syncthreads();
  for (int idx = tid; idx < 2048; idx += 256) {
    int j = idx >> 5, c2 = (idx & 31)*2;
    *(double2*)&kv[j][c2] = *(const double2*)(v + ((size_t)bh*1024 + tk[j])*64 + c2);
  }
  __syncthreads();
  double ov[8];
  #pragma unroll
  for (int dd=0;dd<8;++dd) ov[dd]=0.0;
  for (int j=0;j<64;++j) {
    double p = pp[i][j];
    #pragma unroll
    for (int dd=0;dd<8;++dd) ov[dd] += p * kv[j][sub*8+dd];
  }
  double rinv = 1.0 / esum;
  int r = c >> 5;
  size_t ob = (((size_t)bh_l*4 + r)*1024 + ti)*64 + sub*8;
  #pragma unroll
  for (int dd=0;dd<8;++dd) obuf[ob + dd] = ov[dd]*rinv;
  if (sub == 0) lse[((size_t)bh*4 + r)*1024 + ti] = log(esum) + dmax;
}

// ---------------- combine rounds (fp64) ----------------
__global__ __launch_bounds__(256)
void combine_kernel(const double* __restrict__ obuf, const double* __restrict__ lse,
                    double* __restrict__ comb, int bh0) {
  int g = blockIdx.x*4 + (threadIdx.x >> 6);
  int bh_l = g >> 10, t = g & 1023;
  int bh = bh0 + bh_l;
  int d = threadIdx.x & 63;
  double l[4];
  #pragma unroll
  for (int r=0;r<4;++r) l[r] = lse[((size_t)bh*4 + r)*1024 + t];
  double m = fmax(fmax(l[0],l[1]), fmax(l[2],l[3]));
  double e[4], s=0.0;
  #pragma unroll
  for (int r=0;r<4;++r){ e[r]=exp(l[r]-m); s+=e[r]; }
  double rs = 1.0/s;
  double o = 0.0;
  #pragma unroll
  for (int r=0;r<4;++r)
    o += e[r]*rs * obuf[(((size_t)bh_l*4 + r)*1024 + t)*64 + d];
  int b = bh >> 3, hd = bh & 7;
  comb[((size_t)b*1024 + t)*512 + hd*64 + d] = o;
}

// ---------------- chunked LSH attention fp32 (layer-2 value path) ----------------
__global__ __launch_bounds__(256)
void lsh_attn32_kernel(const float* __restrict__ qk, const float* __restrict__ v,
                       const int* __restrict__ sticker,
                       float* __restrict__ obuf, float* __restrict__ lse, int bh0) {
  int bh_l = blockIdx.x >> 7;
  int bh = bh0 + bh_l;
  int c  = blockIdx.x & 127;
  int cprev = (c + 127) & 127;
  __shared__ float kv[64][68];
  __shared__ float pp[32][68];
  __shared__ float rnorm[64];
  __shared__ int tk[64];
  int tid = threadIdx.x;
  if (tid < 64) {
    int chunk = (tid < 32) ? c : cprev;
    tk[tid] = sticker[(size_t)bh*NT_ + chunk*32 + (tid & 31)];
  }
  __syncthreads();
  for (int idx = tid; idx < 1024; idx += 256) {
    int j = idx >> 4, c4 = (idx & 15)*4;
    *(float4*)&kv[j][c4] = *(const float4*)(qk + ((size_t)bh*1024 + tk[j])*64 + c4);
  }
  __syncthreads();
  if (tid < 64) {
    float s = 0.f;
    #pragma unroll
    for (int f=0; f<64; ++f) { float x = kv[tid][f]; s += x*x; }
    rnorm[tid] = 1.0f / fmaxf(sqrtf(s), 1e-12f);
  }
  __syncthreads();
  int i = tid >> 3, sub = tid & 7;
  int ti = tk[i];
  float dots[8];
  float dmax = -1.0e30f;
  #pragma unroll
  for (int jj=0; jj<8; ++jj) {
    int j = sub*8 + jj;
    float s = 0.f;
    #pragma unroll
    for (int f=0; f<64; ++f) s += kv[i][f] * kv[j][f];
    s *= rnorm[j] * 0.125f;
    if (ti == tk[j]) s = MASKSELF32;
    dots[jj] = s;
    dmax = fmaxf(dmax, s);
  }
  #pragma unroll
  for (int w=1; w<8; w<<=1) dmax = fmaxf(dmax, __shfl_xor(dmax, w, 64));
  float esum = 0.f;
  #pragma unroll
  for (int jj=0; jj<8; ++jj) {
    float e = expf(dots[jj] - dmax);
    esum += e;
    pp[i][sub*8+jj] = e;
  }
  #pragma unroll
  for (int w=1; w<8; w<<=1) esum += __shfl_xor(esum, w, 64);
  __syncthreads();
  for (int idx = tid; idx < 1024; idx += 256) {
    int j = idx >> 4, c4 = (idx & 15)*4;
    *(float4*)&kv[j][c4] = *(const float4*)(v + ((size_t)bh*1024 + tk[j])*64 + c4);
  }
  __syncthreads();
  float ov[8];
  #pragma unroll
  for (int dd=0;dd<8;++dd) ov[dd]=0.f;
  for (int j=0;j<64;++j) {
    float p = pp[i][j];
    #pragma unroll
    for (int dd=0;dd<8;++dd) ov[dd] += p * kv[j][sub*8+dd];
  }
  float rinv = 1.0f / esum;
  int r = c >> 5;
  size_t ob = (((size_t)bh_l*4 + r)*1024 + ti)*64 + sub*8;
  #pragma unroll
  for (int dd=0;dd<8;++dd) obuf[ob + dd] = ov[dd]*rinv;
  if (sub == 0) lse[((size_t)bh*4 + r)*1024 + ti] = logf(esum) + dmax;
}

// ---------------- combine rounds (fp32) ----------------
__global__ __launch_bounds__(256)
void combine32_kernel(const float* __restrict__ obuf, const float* __restrict__ lse,
                      float* __restrict__ comb, int bh0) {
  int g = blockIdx.x*4 + (threadIdx.x >> 6);
  int bh_l = g >> 10, t = g & 1023;
  int bh = bh0 + bh_l;
  int d = threadIdx.x & 63;
  float l[4];
  #pragma unroll
  for (int r=0;r<4;++r) l[r] = lse[((size_t)bh*4 + r)*1024 + t];
  float m = fmaxf(fmaxf(l[0],l[1]), fmaxf(l[2],l[3]));
  float e[4], s=0.f;
  #pragma unroll
  for (int r=0;r<4;++r){ e[r]=expf(l[r]-m); s+=e[r]; }
  float rs = 1.0f/s;
  float o = 0.f;
  #pragma unroll
  for (int r=0;r<4;++r)
    o += e[r]*rs * obuf[(((size_t)bh_l*4 + r)*1024 + t)*64 + d];
  int b = bh >> 3, hd = bh & 7;
  comb[((size_t)b*1024 + t)*512 + hd*64 + d] = o;
}

// ---------------- layernorm fp64 (optional residual, optional f32 dup) ----------------
__global__ __launch_bounds__(256)
void ln_kernel(const double* __restrict__ x, const double* __restrict__ res,
               const float* __restrict__ gw, const float* __restrict__ bw,
               double* __restrict__ outp, float* __restrict__ out32) {
  int row = blockIdx.x;
  int tid = threadIdx.x;
  const double* xr = x + (size_t)row*512;
  double v0 = xr[tid], v1 = xr[tid+256];
  if (res) { const double* rr = res + (size_t)row*512; v0 += rr[tid]; v1 += rr[tid+256]; }
  double s = v0 + v1;
  #pragma unroll
  for (int w=1; w<64; w<<=1) s += __shfl_xor(s, w, 64);
  __shared__ double red[4];
  int wid = tid >> 6, lane = tid & 63;
  if (lane == 0) red[wid] = s;
  __syncthreads();
  s = red[0]+red[1]+red[2]+red[3];
  double m = s * (1.0/512.0);
  double d0 = v0 - m, d1 = v1 - m;
  double q = d0*d0 + d1*d1;
  #pragma unroll
  for (int w=1; w<64; w<<=1) q += __shfl_xor(q, w, 64);
  __syncthreads();
  if (lane == 0) red[wid] = q;
  __syncthreads();
  q = red[0]+red[1]+red[2]+red[3];
  double var = q * (1.0/512.0);
  double rstd = 1.0 / sqrt(var + 1e-5);
  double o0 = d0*rstd*(double)gw[tid] + (double)bw[tid];
  double o1 = d1*rstd*(double)gw[tid+256] + (double)bw[tid+256];
  outp[(size_t)row*512 + tid]       = o0;
  outp[(size_t)row*512 + tid + 256] = o1;
  if (out32) {
    out32[(size_t)row*512 + tid]       = (float)o0;
    out32[(size_t)row*512 + tid + 256] = (float)o1;
  }
}

// ---------------- layernorm: x f64 + res f32 -> f32 ----------------
__global__ __launch_bounds__(256)
void lnmx_kernel(const double* __restrict__ x, const float* __restrict__ res,
                 const float* __restrict__ gw, const float* __restrict__ bw,
                 float* __restrict__ out32) {
  int row = blockIdx.x;
  int tid = threadIdx.x;
  const double* xr = x + (size_t)row*512;
  const float*  rr = res + (size_t)row*512;
  double v0 = xr[tid] + (double)rr[tid];
  double v1 = xr[tid+256] + (double)rr[tid+256];
  double s = v0 + v1;
  #pragma unroll
  for (int w=1; w<64; w<<=1) s += __shfl_xor(s, w, 64);
  __shared__ double red[4];
  int wid = tid >> 6, lane = tid & 63;
  if (lane == 0) red[wid] = s;
  __syncthreads();
  s = red[0]+red[1]+red[2]+red[3];
  double m = s * (1.0/512.0);
  double d0 = v0 - m, d1 = v1 - m;
  double q = d0*d0 + d1*d1;
  #pragma unroll
  for (int w=1; w<64; w<<=1) q += __shfl_xor(q, w, 64);
  __syncthreads();
  if (lane == 0) red[wid] = q;
  __syncthreads();
  q = red[0]+red[1]+red[2]+red[3];
  double rstd = 1.0 / sqrt(q * (1.0/512.0) + 1e-5);
  out32[(size_t)row*512 + tid]       = (float)(d0*rstd*(double)gw[tid] + (double)bw[tid]);
  out32[(size_t)row*512 + tid + 256] = (float)(d1*rstd*(double)gw[tid+256] + (double)bw[tid+256]);
}

// ---------------- layernorm f32 in/out (double stats), optional residual ----------------
__global__ __launch_bounds__(256)
void ln32_kernel(const float* __restrict__ x, const float* __restrict__ res,
                 const float* __restrict__ gw, const float* __restrict__ bw,
                 float* __restrict__ out32) {
  int row = blockIdx.x;
  int tid = threadIdx.x;
  const float* xr = x + (size_t)row*512;
  double v0 = (double)xr[tid], v1 = (double)xr[tid+256];
  if (res) { const float* rr = res + (size_t)row*512; v0 += (double)rr[tid]; v1 += (double)rr[tid+256]; }
  double s = v0 + v1;
  #pragma unroll
  for (int w=1; w<64; w<<=1) s += __shfl_xor(s, w, 64);
  __shared__ double red[4];
  int wid = tid >> 6, lane = tid & 63;
  if (lane == 0) red[wid] = s;
  __syncthreads();
  s = red[0]+red[1]+red[2]+red[3];
  double m = s * (1.0/512.0);
  double d0 = v0 - m, d1 = v1 - m;
  double q = d0*d0 + d1*d1;
  #pragma unroll
  for (int w=1; w<64; w<<=1) q += __shfl_xor(q, w, 64);
  __syncthreads();
  if (lane == 0) red[wid] = q;
  __syncthreads();
  q = red[0]+red[1]+red[2]+red[3];
  double rstd = 1.0 / sqrt(q * (1.0/512.0) + 1e-5);
  out32[(size_t)row*512 + tid]       = (float)(d0*rstd*(double)gw[tid] + (double)bw[tid]);
  out32[(size_t)row*512 + tid + 256] = (float)(d1*rstd*(double)gw[tid+256] + (double)bw[tid+256]);
}

// ---------------- final projection (f32 input, f64 accum, f32 store) ----------------
__global__ __launch_bounds__(64)
void proj_kernel(const float* __restrict__ hf, const float* __restrict__ pw,
                 const float* __restrict__ pb, float* __restrict__ outp) {
  int row = blockIdx.x;
  int b = row >> 8, tp = row & 255;
  const float* hr = hf + ((size_t)b*1024 + 768 + tp)*512;
  int lane = threadIdx.x;
  double acc[7];
  #pragma unroll
  for (int cc=0;cc<7;++cc) acc[cc]=0.0;
  for (int d = lane; d < 512; d += 64) {
    double hv = (double)hr[d];
    #pragma unroll
    for (int cc=0;cc<7;++cc) acc[cc] += hv * (double)pw[d*7 + cc];
  }
  #pragma unroll
  for (int cc=0;cc<7;++cc) {
    double s = acc[cc];
    #pragma unroll
    for (int w=32;w>=1;w>>=1) s += __shfl_xor(s, w, 64);
    if (lane == 0) outp[(size_t)row*7 + cc] = (float)(s + (double)pb[cc]);
  }
}

extern "C" void kernel_launch(void* const* d_in, const int* in_sizes, int n_in,
                              void* d_out, int out_size, void* d_ws, size_t ws_size,
                              hipStream_t stream) {
  (void)in_sizes; (void)n_in; (void)out_size; (void)ws_size;
  const float* x_enc      = (const float*)d_in[0];
  const float* x_mark_enc = (const float*)d_in[1];
  const float* x_dec      = (const float*)d_in[2];
  const float* x_mark_dec = (const float*)d_in[3];
  const float* conv_w     = (const float*)d_in[4];
  const float* mark_w     = (const float*)d_in[5];
  const float* qk_w       = (const float*)d_in[6];
  const float* v_w        = (const float*)d_in[7];
  const float* out_w      = (const float*)d_in[8];
  const float* out_b      = (const float*)d_in[9];
  const float* ln1_g      = (const float*)d_in[10];
  const float* ln1_b      = (const float*)d_in[11];
  const float* ln2_g      = (const float*)d_in[12];
  const float* ln2_b      = (const float*)d_in[13];
  const float* ffn_w1     = (const float*)d_in[14];
  const float* ffn_b1     = (const float*)d_in[15];
  const float* ffn_w2     = (const float*)d_in[16];
  const float* ffn_b2     = (const float*)d_in[17];
  const float* lnf_g      = (const float*)d_in[18];
  const float* lnf_b      = (const float*)d_in[19];
  const float* proj_w     = (const float*)d_in[20];
  const float* proj_b     = (const float*)d_in[21];
  const float* rotations  = (const float*)d_in[22];

  char* ws = (char*)d_ws;
  // regions: A [0,64M) B [64,128M) C [128,192M) D [192,224M)
  double* h64   = (double*)(ws);               // A
  double* qk64  = (double*)(ws + 67108864);    // B: qk64 / ffn1 hidden slice
  double* v64   = (double*)(ws + 134217728);   // C: v64 / comb / ffn2 accumulator
  double* obuf  = (double*)(ws + 201326592);   // D: o_rounds (16 bh)
  int*    stick = (int*)   (ws + 234881024);   // [224,226M)
  double* lse64 = (double*)(ws + 236978176);   // [226,230M)
  float*  lse32 = (float*) (ws + 236978176);
  double* comb  = v64;
  // layer-2 f32 aliases
  float* h32    = (float*)(ws + 201326592);    // D    (obuf dead after layer-1 attn)
  float* qk32   = (float*)(ws + 134217728);    // C0 [128,160)
  float* v32    = (float*)(ws + 167772160);    // C1 [160,192)
  float* obuf32 = (float*)(ws + 67108864);     // B0 [64,96)   (qk64 dead after bucket_sort)
  float* comb32 = (float*)(ws + 100663296);    // B1 [96,128)
  float* ao32   = (float*)(ws + 201326592);    // D   (h32 dead after v-GEMM)
  float* hA32   = (float*)(ws + 134217728);    // C0  (qk32 dead after attn)
  float* hid32  = (float*)(ws);                // A+B [0,128M) full f32 hidden
  float* y32    = (float*)(ws + 167772160);    // C1  (v32 dead)
  float* h2f    = (float*)(ws + 201326592);    // D   (ao32 dead)
  float* hf32   = (float*)(ws);                // A0 [0,32M) (hid32 dead)

  embed_kernel<<<16384, 256, 0, stream>>>(x_enc, x_mark_enc, x_dec, x_mark_dec,
                                          conv_w, mark_w, h64);

  // ================= layer 0 : full fp64 =================
  dgemm_kernel<<<dim3(128,4), 256, 0, stream>>>(h64, qk_w, nullptr, qk64, nullptr,
                                                512, 512, 512, 4);
  dgemm_kernel<<<dim3(128,4), 256, 0, stream>>>(h64, v_w, nullptr, v64, nullptr,
                                                512, 512, 512, 4);
  bucket_sort_kernel<<<512, 256, 0, stream>>>(qk64, rotations, stick);
  for (int g = 0; g < 8; ++g) {
    lsh_attn_kernel<<<2048, 256, 0, stream>>>(qk64, v64, stick, obuf, lse64, g*16);
    combine_kernel<<<4096, 256, 0, stream>>>(obuf, lse64, comb, g*16);
  }
  dgemm_kernel<<<dim3(128,4), 256, 0, stream>>>(comb, out_w, out_b, qk64, nullptr,
                                                512, 512, 512, 1);
  ln_kernel<<<16384, 256, 0, stream>>>(h64, qk64, ln1_g, ln1_b, h64, nullptr);
  for (int c = 0; c < 4; ++c) {   // FFN col-chunked: hidden slice [16384][512] f64 in qk64
    dgemm_kernel<<<dim3(128,4), 256, 0, stream>>>(h64, ffn_w1 + c*512,
                                                  ffn_b1 + c*512, qk64, nullptr,
                                                  512, 512, 2048, 3);
    dgemm_kernel<<<dim3(128,4), 256, 0, stream>>>(qk64, ffn_w2 + (size_t)c*512*512,
                                                  ffn_b2, comb, nullptr,
                                                  512, 512, 512, (c == 0) ? 1 : 16);
  }
  ln_kernel<<<16384, 256, 0, stream>>>(h64, comb, ln2_g, ln2_b, h64, h32);

  // ================= layer 1 : f64 decisions, f32 values =================
  sgemm_kernel<<<dim3(128,4), 256, 0, stream>>>(h32, v_w + 262144, nullptr, v32,
                                                512, 512, 4);
  dgemm_kernel<<<dim3(128,4), 256, 0, stream>>>(h64, qk_w + 262144, nullptr, qk64, qk32,
                                                512, 512, 512, 4 | 8);
  bucket_sort_kernel<<<512, 256, 0, stream>>>(qk64, rotations + 4096, stick);
  for (int g = 0; g < 4; ++g) {
    lsh_attn32_kernel<<<4096, 256, 0, stream>>>(qk32, v32, stick, obuf32, lse32, g*32);
    combine32_kernel<<<8192, 256, 0, stream>>>(obuf32, lse32, comb32, g*32);
  }
  sgemm_kernel<<<dim3(128,4), 256, 0, stream>>>(comb32, out_w + 262144, out_b + 512,
                                                ao32, 512, 512, 1);
  lnmx_kernel<<<16384, 256, 0, stream>>>(h64, ao32, ln1_g + 512, ln1_b + 512, hA32);
  sgemm_kernel<<<dim3(128,16), 256, 0, stream>>>(hA32, ffn_w1 + 1048576, ffn_b1 + 2048,
                                                 hid32, 2048, 512, 3);
  sgemm_kernel<<<dim3(128,4), 256, 0, stream>>>(hid32, ffn_w2 + 1048576, ffn_b2 + 512,
                                                y32, 512, 2048, 1);
  ln32_kernel<<<16384, 256, 0, stream>>>(hA32, y32, ln2_g + 512, ln2_b + 512, h2f);
  ln32_kernel<<<16384, 256, 0, stream>>>(h2f, nullptr, lnf_g, lnf_b, hf32);
  proj_kernel<<<4096, 64, 0, stream>>>(hf32, proj_w, proj_b, (float*)d_out);
}